// Round 11
// baseline (491.005 us; speedup 1.0000x reference)
//
#include <hip/hip_runtime.h>

typedef unsigned short u16;
typedef __attribute__((ext_vector_type(8))) short bf16x8;
typedef __attribute__((ext_vector_type(4))) float f32x4;

#define INV_SCALE 0.17677669529663687f

static __device__ __forceinline__ float b2f(u16 u) {
    union { unsigned int i; float f; } v; v.i = ((unsigned int)u) << 16; return v.f;
}
static __device__ __forceinline__ u16 f2b(float f) {
    union { float f; unsigned int i; } v; v.f = f;
    unsigned int r = (v.i + 0x7FFFu + ((v.i >> 16) & 1u)) >> 16;
    return (u16)r;
}

// ---- param arena segment table (bf16 elements), shared host/device ----
// Weight segs 7-11 (128x128/layer), 15 (W1), 17 (W2) are stored TRANSPOSED [n][k].
#define NSEG 23
__device__ __constant__ int d_seg_off[NSEG + 1] = {
    0, 8192, 270336, 272384, 272512, 273536, 273664, 273792, 322944, 372096,
    421248, 470400, 519552, 519936, 520320, 520704, 717312, 718848, 915456,
    915840, 916224, 916608, 916736, 916744};
static const int h_seg_off[NSEG + 1] = {
    0, 8192, 270336, 272384, 272512, 273536, 273664, 273792, 322944, 372096,
    421248, 470400, 519552, 519936, 520320, 520704, 717312, 718848, 915456,
    915840, 916224, 916608, 916736, 916744};
#define ARENA_TOTAL 916744

struct ParamPtrs { const void* p[NSEG]; };

// ---------------------------------------------------------------- param convert + mask probe
__global__ __launch_bounds__(256) void convert_params(ParamPtrs pp, u16* __restrict__ arena,
                                                      const void* __restrict__ mask,
                                                      int* __restrict__ mode) {
    if (blockIdx.x == 0) {
        __shared__ int f16, f32s, u8s;
        int tid = threadIdx.x;
        if (tid == 0) { f16 = 0; f32s = 0; u8s = 0; }
        __syncthreads();
        const u16* mu = (const u16*)mask;
        const unsigned int* mw = (const unsigned int*)mask;
        if (mu[2 * tid] == 0x3F80u) atomicOr(&f16, 1);
        if (mw[tid] == 0x3F800000u) atomicOr(&f32s, 1);
        if (mw[tid] > 1u) atomicOr(&u8s, 1);
        __syncthreads();
        if (tid == 0) mode[0] = f16 ? 0 : (f32s ? 3 : (u8s ? 1 : 2));
    }
    const unsigned int probe = ((const unsigned int*)pp.p[13])[0];   // ln1_g[0] == 1.0
    const bool f32 = (probe == 0x3F800000u);
    for (int e = blockIdx.x * 256 + threadIdx.x; e < ARENA_TOTAL; e += gridDim.x * 256) {
        int k = 0;
        #pragma unroll
        for (int s2 = 1; s2 < NSEG; ++s2) if (e >= d_seg_off[s2]) k = s2;
        int local = e - d_seg_off[k];
        // transposed weight segments: arena [l][n][k] <- src [l][k][n]
        int src = local;
        if (k >= 7 && k <= 11) {                 // [L][128k][128n] -> [L][128n][128k]
            int l = local >> 14, rem = local & 16383;
            int n = rem >> 7, kk = rem & 127;
            src = (l << 14) + kk * 128 + n;
        } else if (k == 15) {                    // W1 [L][128k][512n] -> [L][512n][128k]
            int l = local >> 16, rem = local & 65535;
            int n = rem >> 7, kk = rem & 127;
            src = (l << 16) + kk * 512 + n;
        } else if (k == 17) {                    // W2 [L][512k][128n] -> [L][128n][512k]
            int l = local >> 16, rem = local & 65535;
            int n = rem >> 9, kk = rem & 511;
            src = (l << 16) + kk * 128 + n;
        }
        u16 v;
        if (k == 22 && local >= 1) v = 0;   // bout padded 1 -> 8
        else v = f32 ? f2b(((const float*)pp.p[k])[src]) : ((const u16*)pp.p[k])[src];
        arena[e] = v;
    }
}

// ---------------------------------------------------------------- tok assembly (mask fused)
__global__ __launch_bounds__(256) void assemble_kernel(
    const u16* __restrict__ x, const u16* __restrict__ ea,
    const void* __restrict__ mask, const int* __restrict__ modeptr,
    const u16* __restrict__ nodeW, const u16* __restrict__ nodeB,
    const u16* __restrict__ edgeW, const u16* __restrict__ edgeB, const u16* __restrict__ noedge,
    float* __restrict__ tokf, u16* __restrict__ tokb)
{
    const int md = modeptr[0];
    int g = blockIdx.x * 256 + threadIdx.x;      // [0, 1048576)
    int t = g >> 5, dq = g & 31, d0 = dq * 4;
    int b = t >> 12, i = (t >> 6) & 63, j = t & 63;
    float v[4];
    if (i == j) {
        #pragma unroll
        for (int c = 0; c < 4; c++) v[c] = b2f(nodeB[d0 + c]);
        #pragma unroll
        for (int e = 0; e < 16; e++) {
            float xe = b2f(x[(b * 64 + i) * 16 + e]);
            #pragma unroll
            for (int c = 0; c < 4; c++) v[c] += xe * b2f(nodeW[e * 128 + d0 + c]);
        }
    } else {
        bool edge;
        if (md == 0)      edge = ((const u16*)mask)[t] != 0;
        else if (md == 3) edge = ((const float*)mask)[t] != 0.0f;
        else if (md == 1) edge = ((const unsigned char*)mask)[t] != 0;
        else              edge = ((const unsigned int*)mask)[t] != 0;
        if (edge) {
            #pragma unroll
            for (int c = 0; c < 4; c++) v[c] = b2f(edgeB[d0 + c]);
            #pragma unroll
            for (int e = 0; e < 8; e++) {
                float ae = b2f(ea[t * 8 + e]);
                #pragma unroll
                for (int c = 0; c < 4; c++) v[c] += ae * b2f(edgeW[e * 128 + d0 + c]);
            }
        } else {
            #pragma unroll
            for (int c = 0; c < 4; c++) v[c] = b2f(noedge[d0 + c]);
        }
    }
    *(float4*)(tokf + (size_t)t * 128 + d0) = make_float4(v[0], v[1], v[2], v[3]);
    u16 pk[4];
    #pragma unroll
    for (int c = 0; c < 4; c++) pk[c] = f2b(v[c]);
    *(uint2*)(tokb + (size_t)t * 128 + d0) = *(uint2*)pk;
}

// ---------------------------------------------------------------- qkv GEMM (BM=128, 256 thr, 4 waves)
// B transposed [128 n][128 k]; vector uint4 staging. by: 0=q 1=k 2=v1(fp32) 3=v2.
__global__ __launch_bounds__(256) void gemm_qkv_kernel(
    const u16* __restrict__ A,
    const u16* __restrict__ B0, const u16* __restrict__ B1,
    const u16* __restrict__ B2, const u16* __restrict__ B3,
    float* __restrict__ v1f,
    u16* __restrict__ qb, u16* __restrict__ kb, u16* __restrict__ v2b)
{
    __shared__ __align__(16) u16 smem[2 * 128 * 72];   // 36864 B
    u16* As = smem;
    u16* Bs = smem + 128 * 72;
    int tid = threadIdx.x;
    int m0 = blockIdx.x * 128;
    int by = blockIdx.y;
    const u16* Bp = (by == 0) ? B0 : (by == 1) ? B1 : (by == 2) ? B2 : B3;

    int w = tid >> 6, lane = tid & 63;
    int q = lane >> 4, r16 = lane & 15;
    int rw = (w >> 1) * 64, cw = (w & 1) * 64;

    f32x4 acc[4][4];
    #pragma unroll
    for (int mi = 0; mi < 4; mi++)
        #pragma unroll
        for (int ni = 0; ni < 4; ni++) acc[mi][ni] = (f32x4){0.f, 0.f, 0.f, 0.f};

    #pragma unroll
    for (int kt = 0; kt < 2; ++kt) {
        int k0 = kt * 64;
        __syncthreads();
        #pragma unroll
        for (int it = 0; it < 4; ++it) {               // A: 128 x 64 (1024 uint4)
            int idx = tid + it * 256;
            int row = idx >> 3, ch = idx & 7;
            uint4 d = *(const uint4*)(A + (size_t)(m0 + row) * 128 + k0 + ch * 8);
            *(uint4*)&As[row * 72 + ch * 8] = d;
        }
        #pragma unroll
        for (int it = 0; it < 4; ++it) {               // B^T: 128 n x 64 k (1024 uint4)
            int idx = tid + it * 256;
            int n = idx >> 3, ch = idx & 7;
            uint4 d = *(const uint4*)(Bp + (size_t)n * 128 + k0 + ch * 8);
            int ch2 = ch ^ ((n >> 3) & 7);
            *(uint4*)&Bs[n * 72 + ch2 * 8] = d;
        }
        __syncthreads();
        #pragma unroll
        for (int ks = 0; ks < 2; ++ks) {
            bf16x8 fa[4], fb[4];
            #pragma unroll
            for (int mi = 0; mi < 4; mi++)
                fa[mi] = *(const bf16x8*)&As[(rw + mi * 16 + r16) * 72 + ks * 32 + q * 8];
            #pragma unroll
            for (int ni = 0; ni < 4; ni++) {
                int n = cw + ni * 16 + r16;
                int ch2 = (ks * 4 + q) ^ ((n >> 3) & 7);
                fb[ni] = *(const bf16x8*)&Bs[n * 72 + ch2 * 8];
            }
            #pragma unroll
            for (int mi = 0; mi < 4; mi++)
                #pragma unroll
                for (int ni = 0; ni < 4; ni++)
                    acc[mi][ni] = __builtin_amdgcn_mfma_f32_16x16x32_bf16(fa[mi], fb[ni], acc[mi][ni], 0, 0, 0);
        }
    }

    // ---------------- epilogue (scatter) ----------------
    int bl = m0 >> 12, it0 = (m0 >> 6) & 63;
    __syncthreads();
    if (by == 2) {
        // ---- v1f fp32 scatter: [bh][i][l][32] ----
        float* cf = (float*)smem;                      // [128][64] fp32, XOR-swizzled
        #pragma unroll
        for (int hp = 0; hp < 2; ++hp) {
            if (hp) __syncthreads();
            if ((cw >> 6) == hp) {
                #pragma unroll
                for (int mi = 0; mi < 4; mi++) {
                    #pragma unroll
                    for (int ni = 0; ni < 4; ni++) {
                        int colh = (cw & 63) + ni * 16 + r16;
                        int ch4 = colh >> 2, cl = colh & 3;
                        #pragma unroll
                        for (int rr = 0; rr < 4; rr++) {
                            int r = rw + mi * 16 + q * 4 + rr;
                            cf[r * 64 + (((ch4 ^ (r & 15)) << 2) | cl)] = acc[mi][ni][rr];
                        }
                    }
                }
            }
            __syncthreads();
            #pragma unroll
            for (int it = 0; it < 8; ++it) {
                int idx = tid + it * 256;          // (hh:1 | itl:1 | jt:6 | d4:3)
                int hh = idx >> 10, itl = (idx >> 9) & 1, jt = (idx >> 3) & 63, d4 = idx & 7;
                int r = itl * 64 + jt;
                int colh = hh * 32 + d4 * 4;
                f32x4 v = *(const f32x4*)&cf[r * 64 + (((colh >> 2) ^ (r & 15)) << 2)];
                int h = hp * 2 + hh;
                *(f32x4*)&v1f[((((size_t)(bl * 4 + h)) * 64 + it0 + itl) * 64 + jt) * 32 + d4 * 4] = v;
            }
        }
    } else {
        // ---- bf16 scatter paths: q/k/v2 ----
        u16* cs = smem;                                // [128][128] u16, XOR-swizzled
        #pragma unroll
        for (int mi = 0; mi < 4; mi++) {
            #pragma unroll
            for (int ni = 0; ni < 4; ni++) {
                int col = cw + ni * 16 + r16;
                int ch = col >> 3, cl = col & 7;
                #pragma unroll
                for (int rr = 0; rr < 4; rr++) {
                    int r = rw + mi * 16 + q * 4 + rr;
                    cs[r * 128 + (((ch ^ (r & 15)) << 3) | cl)] = f2b(acc[mi][ni][rr]);
                }
            }
        }
        __syncthreads();
        if (by == 0) {                                 // q: [bh][l=jt][i][32]
            #pragma unroll
            for (int it = 0; it < 8; ++it) {
                int idx = tid + it * 256;              // (h:2 | jt:6 | itl:1 | d8:2)
                int h = idx >> 9, jt = (idx >> 3) & 63, itl = (idx >> 2) & 1, d8 = idx & 3;
                int r = itl * 64 + jt, c8 = h * 4 + d8;
                uint4 d = *(const uint4*)&cs[r * 128 + ((c8 ^ (r & 15)) << 3)];
                *(uint4*)&qb[((((size_t)(bl * 4 + h)) * 64 + jt) * 64 + it0 + itl) * 32 + d8 * 8] = d;
            }
        } else {                                       // k / v2: [bh][i][j=jt][32]
            u16* dp = (by == 1) ? kb : v2b;
            #pragma unroll
            for (int it = 0; it < 8; ++it) {
                int idx = tid + it * 256;              // (h:2 | itl:1 | jt:6 | d8:2)
                int h = idx >> 9, itl = (idx >> 8) & 1, jt = (idx >> 2) & 63, d8 = idx & 3;
                int r = itl * 64 + jt, c8 = h * 4 + d8;
                uint4 d = *(const uint4*)&cs[r * 128 + ((c8 ^ (r & 15)) << 3)];
                *(uint4*)&dp[((((size_t)(bl * 4 + h)) * 64 + it0 + itl) * 64 + jt) * 32 + d8 * 8] = d;
            }
        }
    }
}

// ---------------------------------------------------------------- fused layer-second-half:
// Wo GEMM + bias + residual + LN1 -> (regs + LDS bf16) -> FF1(relu) -> FF2 + residual + LN2 -> tokf/tokb
// BM=64, 256 thr (4 waves). All B-panel staging register-prefetched (load chunk i+1 during MFMA of i).
__global__ __launch_bounds__(256) void fuse2_kernel(
    const u16* __restrict__ A,                     // ob rows [.][128]
    const u16* __restrict__ WoT, const u16* __restrict__ bo,
    const u16* __restrict__ g1, const u16* __restrict__ be1,
    const u16* __restrict__ W1T, const u16* __restrict__ b1,   // W1T [512][128]
    const u16* __restrict__ W2T, const u16* __restrict__ b2,   // W2T [128][512]
    const u16* __restrict__ g2, const u16* __restrict__ be2,
    float* __restrict__ tokf, u16* __restrict__ tokbO)
{
    __shared__ __align__(16) u16 smem[9216 + 9216 + 4608];   // 46080 B
    u16* As = smem;            // [2 kt][64 r][72]  LN1 bf16 (persistent through FF)
    u16* Bs = smem + 9216;     // [128 n][72]       current B chunk
    u16* Hs = smem + 18432;    // [64 r][72]        A-chunk / h-chunk staging; rsm overlay
    int tid = threadIdx.x;
    int m0 = blockIdx.x * 64;
    int w = tid >> 6, lane = tid & 63;
    int q = lane >> 4, r16 = lane & 15;
    int rw = (w >> 1) * 32, cw = (w & 1) * 64;
    int half_w = cw >> 6;

    // staging index precompute
    int bn[4], bch[4], bch2[4];
    #pragma unroll
    for (int it = 0; it < 4; ++it) {
        int idx = tid + it * 256;
        bn[it] = idx >> 3; bch[it] = idx & 7;
        bch2[it] = bch[it] ^ ((bn[it] >> 3) & 7);
    }
    int an[2], ach[2];
    #pragma unroll
    for (int it = 0; it < 2; ++it) {
        int idx = tid + it * 256;
        an[it] = idx >> 3; ach[it] = idx & 7;
    }

    uint4 pb[4], pa[2];

#define LDB(ptr_, ldr_, roff_, coff_)                                               \
    do {                                                                            \
        _Pragma("unroll")                                                           \
        for (int it = 0; it < 4; ++it)                                              \
            pb[it] = *(const uint4*)((ptr_) + (size_t)((roff_) + bn[it]) * (ldr_) + (coff_) + bch[it] * 8); \
    } while (0)
#define STB()                                                                       \
    do {                                                                            \
        _Pragma("unroll")                                                           \
        for (int it = 0; it < 4; ++it)                                              \
            *(uint4*)&Bs[bn[it] * 72 + bch2[it] * 8] = pb[it];                      \
    } while (0)
#define LDA(kt_)                                                                    \
    do {                                                                            \
        _Pragma("unroll")                                                           \
        for (int it = 0; it < 2; ++it)                                              \
            pa[it] = *(const uint4*)(A + (size_t)(m0 + an[it]) * 128 + (kt_) * 64 + ach[it] * 8); \
    } while (0)
#define STA()                                                                       \
    do {                                                                            \
        _Pragma("unroll")                                                           \
        for (int it = 0; it < 2; ++it)                                              \
            *(uint4*)&Hs[an[it] * 72 + ach[it] * 8] = pa[it];                       \
    } while (0)

    // ================= Wo GEMM (A from Hs, B from Bs) =================
    f32x4 acc[2][4];
    #pragma unroll
    for (int mi = 0; mi < 2; mi++)
        #pragma unroll
        for (int ni = 0; ni < 4; ni++) acc[mi][ni] = (f32x4){0.f, 0.f, 0.f, 0.f};

    LDA(0); LDB(WoT, 128, 0, 0);
    #pragma unroll
    for (int kt = 0; kt < 2; ++kt) {
        if (kt) __syncthreads();
        STA(); STB();
        if (kt == 0) { LDA(1); LDB(WoT, 128, 0, 64); }
        else         { LDB(W1T, 128, 0, 0); }          // prefetch W1 hs0 kt0
        __syncthreads();
        #pragma unroll
        for (int ks = 0; ks < 2; ++ks) {
            bf16x8 fa[2], fb[4];
            #pragma unroll
            for (int mi = 0; mi < 2; mi++)
                fa[mi] = *(const bf16x8*)&Hs[(rw + mi * 16 + r16) * 72 + ks * 32 + q * 8];
            #pragma unroll
            for (int ni = 0; ni < 4; ni++) {
                int n = cw + ni * 16 + r16;
                int ch2 = (ks * 4 + q) ^ ((n >> 3) & 7);
                fb[ni] = *(const bf16x8*)&Bs[n * 72 + ch2 * 8];
            }
            #pragma unroll
            for (int mi = 0; mi < 2; mi++)
                #pragma unroll
                for (int ni = 0; ni < 4; ni++)
                    acc[mi][ni] = __builtin_amdgcn_mfma_f32_16x16x32_bf16(fa[mi], fb[ni], acc[mi][ni], 0, 0, 0);
        }
    }

    // ================= bias + residual + LN1 (result kept in acc regs) =================
    #pragma unroll
    for (int ni = 0; ni < 4; ni++) {
        int col = cw + ni * 16 + r16;
        float bb = b2f(bo[col]);
        #pragma unroll
        for (int mi = 0; mi < 2; mi++)
            #pragma unroll
            for (int rr = 0; rr < 4; rr++) {
                int r = rw + mi * 16 + q * 4 + rr;
                acc[mi][ni][rr] += bb + tokf[(size_t)(m0 + r) * 128 + col];
            }
    }
    __syncthreads();                                   // Hs MFMA reads done -> rsm overlay safe
    {
        float* rsm = (float*)Hs;                       // [2][64]
        float* rqm = rsm + 128;
        #pragma unroll
        for (int mi = 0; mi < 2; mi++)
            #pragma unroll
            for (int rr = 0; rr < 4; rr++) {
                float s = 0.f, sq = 0.f;
                #pragma unroll
                for (int ni = 0; ni < 4; ni++) { float t = acc[mi][ni][rr]; s += t; sq += t * t; }
                #pragma unroll
                for (int off = 1; off < 16; off <<= 1) {
                    s  += __shfl_xor(s,  off, 16);
                    sq += __shfl_xor(sq, off, 16);
                }
                if (r16 == 0) {
                    int r = rw + mi * 16 + q * 4 + rr;
                    rsm[half_w * 64 + r] = s;
                    rqm[half_w * 64 + r] = sq;
                }
            }
        __syncthreads();
        float gl[4], bv[4];
        #pragma unroll
        for (int ni = 0; ni < 4; ni++) {
            int col = cw + ni * 16 + r16;
            gl[ni] = b2f(g1[col]);
            bv[ni] = b2f(be1[col]);
        }
        #pragma unroll
        for (int mi = 0; mi < 2; mi++)
            #pragma unroll
            for (int rr = 0; rr < 4; rr++) {
                int r = rw + mi * 16 + q * 4 + rr;
                float tot = rsm[r] + rsm[64 + r];
                float tq  = rqm[r] + rqm[64 + r];
                float mean = tot * 0.0078125f;
                float var  = tq * 0.0078125f - mean * mean;
                float rstd = rsqrtf(var + 1e-5f);
                #pragma unroll
                for (int ni = 0; ni < 4; ni++)
                    acc[mi][ni][rr] = (acc[mi][ni][rr] - mean) * rstd * gl[ni] + bv[ni];
            }
        // write bf16 LN1 into As [kt=half_w][row][col&63]
        #pragma unroll
        for (int mi = 0; mi < 2; mi++)
            #pragma unroll
            for (int ni = 0; ni < 4; ni++) {
                int cl = ni * 16 + r16;                // col within half
                #pragma unroll
                for (int rr = 0; rr < 4; rr++) {
                    int r = rw + mi * 16 + q * 4 + rr;
                    As[half_w * 4608 + r * 72 + cl] = f2b(acc[mi][ni][rr]);
                }
            }
    }
    __syncthreads();                                   // As ready; rsm reads done (Hs reusable)

    // ================= FF: acc2 = relu(LN1 @ W1 + b1) @ W2 =================
    f32x4 acc2[2][4];
    #pragma unroll
    for (int mi = 0; mi < 2; mi++)
        #pragma unroll
        for (int ni = 0; ni < 4; ni++) acc2[mi][ni] = (f32x4){0.f, 0.f, 0.f, 0.f};

    for (int hs = 0; hs < 4; ++hs) {
        f32x4 acc1[2][4];
        #pragma unroll
        for (int mi = 0; mi < 2; mi++)
            #pragma unroll
            for (int ni = 0; ni < 4; ni++) acc1[mi][ni] = (f32x4){0.f, 0.f, 0.f, 0.f};
        // ---- GEMM1: LN1(As) x W1 slice ----
        #pragma unroll
        for (int kt = 0; kt < 2; ++kt) {
            if (hs || kt) __syncthreads();             // prev Bs readers done (hs0,kt0 covered by As-ready sync)
            STB();                                     // pb holds W1[hs][kt] (prefetched)
            if (kt == 0) { LDB(W1T, 128, hs * 128, 64); }
            else         { LDB(W2T, 512, 0, hs * 128); }   // W2 half0
            __syncthreads();
            #pragma unroll
            for (int ks = 0; ks < 2; ++ks) {
                bf16x8 fa[2], fb[4];
                #pragma unroll
                for (int mi = 0; mi < 2; mi++)
                    fa[mi] = *(const bf16x8*)&As[kt * 4608 + (rw + mi * 16 + r16) * 72 + ks * 32 + q * 8];
                #pragma unroll
                for (int ni = 0; ni < 4; ni++) {
                    int n = cw + ni * 16 + r16;
                    int ch2 = (ks * 4 + q) ^ ((n >> 3) & 7);
                    fb[ni] = *(const bf16x8*)&Bs[n * 72 + ch2 * 8];
                }
                #pragma unroll
                for (int mi = 0; mi < 2; mi++)
                    #pragma unroll
                    for (int ni = 0; ni < 4; ni++)
                        acc1[mi][ni] = __builtin_amdgcn_mfma_f32_16x16x32_bf16(fa[mi], fb[ni], acc1[mi][ni], 0, 0, 0);
            }
        }
        // ---- GEMM2: relu(acc1+b1) (Hs) x W2 slice ----
        #pragma unroll
        for (int half = 0; half < 2; ++half) {
            __syncthreads();                           // Bs readers + prev Hs readers done
            if ((w & 1) == half) {                     // 2 waves own these 64 hidden cols
                #pragma unroll
                for (int mi = 0; mi < 2; mi++)
                    #pragma unroll
                    for (int ni = 0; ni < 4; ni++) {
                        int kl = ni * 16 + r16;
                        float bb = b2f(b1[hs * 128 + half * 64 + kl]);
                        #pragma unroll
                        for (int rr = 0; rr < 4; rr++) {
                            int row = rw + mi * 16 + q * 4 + rr;
                            Hs[row * 72 + kl] = f2b(fmaxf(acc1[mi][ni][rr] + bb, 0.f));
                        }
                    }
            }
            STB();                                     // pb holds W2[hs][half] (prefetched)
            if (half == 0)   { LDB(W2T, 512, 0, hs * 128 + 64); }
            else if (hs < 3) { LDB(W1T, 128, (hs + 1) * 128, 0); }
            __syncthreads();
            #pragma unroll
            for (int ks = 0; ks < 2; ++ks) {
                bf16x8 fa[2], fb[4];
                #pragma unroll
                for (int mi = 0; mi < 2; mi++)
                    fa[mi] = *(const bf16x8*)&Hs[(rw + mi * 16 + r16) * 72 + ks * 32 + q * 8];
                #pragma unroll
                for (int ni = 0; ni < 4; ni++) {
                    int n = cw + ni * 16 + r16;
                    int ch2 = (ks * 4 + q) ^ ((n >> 3) & 7);
                    fb[ni] = *(const bf16x8*)&Bs[n * 72 + ch2 * 8];
                }
                #pragma unroll
                for (int mi = 0; mi < 2; mi++)
                    #pragma unroll
                    for (int ni = 0; ni < 4; ni++)
                        acc2[mi][ni] = __builtin_amdgcn_mfma_f32_16x16x32_bf16(fa[mi], fb[ni], acc2[mi][ni], 0, 0, 0);
            }
        }
    }

    // ================= bias b2 + residual(LN1 regs) + LN2 -> tokf + tokbO =================
    __syncthreads();                                   // all As/Bs/Hs readers done
    float* cf   = (float*)smem;                        // overlays As (17408 B <= 18432)
    float* rsm2 = cf + 64 * 64;
    float* rqm2 = rsm2 + 128;
    #pragma unroll
    for (int ni = 0; ni < 4; ni++) {
        int col = cw + ni * 16 + r16;
        float bb = b2f(b2[col]);
        #pragma unroll
        for (int mi = 0; mi < 2; mi++)
            #pragma unroll
            for (int rr = 0; rr < 4; rr++)
                acc2[mi][ni][rr] += bb + acc[mi][ni][rr];   // residual = LN1 fp32 regs
    }
    #pragma unroll
    for (int mi = 0; mi < 2; mi++)
        #pragma unroll
        for (int rr = 0; rr < 4; rr++) {
            float s = 0.f, sq = 0.f;
            #pragma unroll
            for (int ni = 0; ni < 4; ni++) { float t = acc2[mi][ni][rr]; s += t; sq += t * t; }
            #pragma unroll
            for (int off = 1; off < 16; off <<= 1) {
                s  += __shfl_xor(s,  off, 16);
                sq += __shfl_xor(sq, off, 16);
            }
            if (r16 == 0) {
                int r = rw + mi * 16 + q * 4 + rr;
                rsm2[half_w * 64 + r] = s;
                rqm2[half_w * 64 + r] = sq;
            }
        }
    __syncthreads();
    {
        float gl[4], bv[4];
        #pragma unroll
        for (int ni = 0; ni < 4; ni++) {
            int col = cw + ni * 16 + r16;
            gl[ni] = b2f(g2[col]);
            bv[ni] = b2f(be2[col]);
        }
        #pragma unroll
        for (int mi = 0; mi < 2; mi++)
            #pragma unroll
            for (int rr = 0; rr < 4; rr++) {
                int r = rw + mi * 16 + q * 4 + rr;
                float tot = rsm2[r] + rsm2[64 + r];
                float tq  = rqm2[r] + rqm2[64 + r];
                float mean = tot * 0.0078125f;
                float var  = tq * 0.0078125f - mean * mean;
                float rstd = rsqrtf(var + 1e-5f);
                #pragma unroll
                for (int ni = 0; ni < 4; ni++)
                    acc2[mi][ni][rr] = (acc2[mi][ni][rr] - mean) * rstd * gl[ni] + bv[ni];
            }
    }
    #pragma unroll
    for (int hp = 0; hp < 2; ++hp) {
        __syncthreads();
        if (half_w == hp) {
            #pragma unroll
            for (int mi = 0; mi < 2; mi++)
                #pragma unroll
                for (int ni = 0; ni < 4; ni++) {
                    int colh = (cw & 63) + ni * 16 + r16;
                    int ch4 = colh >> 2, cl = colh & 3;
                    #pragma unroll
                    for (int rr = 0; rr < 4; rr++) {
                        int r = rw + mi * 16 + q * 4 + rr;
                        cf[r * 64 + (((ch4 ^ (r & 15)) << 2) | cl)] = acc2[mi][ni][rr];
                    }
                }
        }
        __syncthreads();
        #pragma unroll
        for (int it = 0; it < 4; ++it) {
            int idx = tid + it * 256;              // (r:6 | c4:4)
            int r = idx >> 4, c4 = idx & 15;
            f32x4 v = *(const f32x4*)&cf[r * 64 + ((c4 ^ (r & 15)) << 2)];
            int col = hp * 64 + c4 * 4;
            *(f32x4*)(tokf + (size_t)(m0 + r) * 128 + col) = v;
            u16 pk[4];
            #pragma unroll
            for (int e = 0; e < 4; e++) pk[e] = f2b(v[e]);
            *(uint2*)(tokbO + (size_t)(m0 + r) * 128 + col) = *(uint2*)pk;
        }
    }
#undef LDB
#undef STB
#undef LDA
#undef STA
}

// ---------------------------------------------------------------- s = QK^T/scale (bf16 out, raw logits)
__global__ __launch_bounds__(64) void attn_s_kernel(
    const u16* __restrict__ qb, const u16* __restrict__ kb, u16* __restrict__ s)
{
    __shared__ __align__(16) u16 sm[64 * 80];          // qs(64x40) + ks(64x40); reused as cs(64x72)
    u16* qs  = sm;
    u16* ks_ = sm + 64 * 40;
    int g = blockIdx.x;
    int l = g & 63, bh = g >> 6;
    const u16* Q = qb + ((size_t)bh * 64 + l) * 2048;
    const u16* Kp = kb + ((size_t)bh * 64 + l) * 2048;
    int lane = threadIdx.x;
    #pragma unroll
    for (int it = 0; it < 4; ++it) {
        int idx = lane + it * 64;
        int row = idx >> 2, c4 = idx & 3;
        *(uint4*)&qs[row * 40 + c4 * 8] = *(const uint4*)(Q + row * 32 + c4 * 8);
        *(uint4*)&ks_[row * 40 + c4 * 8] = *(const uint4*)(Kp + row * 32 + c4 * 8);
    }
    __syncthreads();
    int q = lane >> 4, r16 = lane & 15;
    f32x4 acc[4][4];
    #pragma unroll
    for (int mi = 0; mi < 4; mi++)
        #pragma unroll
        for (int ni = 0; ni < 4; ni++) acc[mi][ni] = (f32x4){0.f, 0.f, 0.f, 0.f};
    bf16x8 fa[4], fb[4];
    #pragma unroll
    for (int mi = 0; mi < 4; mi++) fa[mi] = *(const bf16x8*)&qs[(mi * 16 + r16) * 40 + q * 8];
    #pragma unroll
    for (int ni = 0; ni < 4; ni++) fb[ni] = *(const bf16x8*)&ks_[(ni * 16 + r16) * 40 + q * 8];
    #pragma unroll
    for (int mi = 0; mi < 4; mi++)
        #pragma unroll
        for (int ni = 0; ni < 4; ni++)
            acc[mi][ni] = __builtin_amdgcn_mfma_f32_16x16x32_bf16(fa[mi], fb[ni], acc[mi][ni], 0, 0, 0);
    // stage C tile in LDS, then coalesced stores
    __syncthreads();
    u16* cs = sm;                                      // 64 x 72
    #pragma unroll
    for (int mi = 0; mi < 4; mi++)
        #pragma unroll
        for (int ni = 0; ni < 4; ni++)
            #pragma unroll
            for (int rr = 0; rr < 4; rr++)
                cs[(mi * 16 + q * 4 + rr) * 72 + ni * 16 + r16] = f2b(acc[mi][ni][rr] * INV_SCALE);
    __syncthreads();
    u16* sb = s + (size_t)bh * 262144 + l * 64;
    #pragma unroll
    for (int it = 0; it < 8; ++it) {
        int row = it * 8 + (lane >> 3);
        uint4 d = *(const uint4*)&cs[row * 72 + (lane & 7) * 8];
        *(uint4*)&sb[(size_t)row * 4096 + (lane & 7) * 8] = d;
    }
}

// ---------------------------------------------------------------- o = softmax_l(s) * v1 * v2  (softmax fused)
// block = (bh, 8-i-group, j-half), 256 threads (4 waves), grid NB*4 x 8 x 2 = 512 -> 2 blocks/CU.
__global__ __launch_bounds__(256) void attn_o_kernel(
    const u16* __restrict__ a, const float* __restrict__ v1f, const u16* __restrict__ v2b,
    u16* __restrict__ ob)
{
    __shared__ __align__(16) float v2s[4 * 1152];   // 18432 B, [l][32 j][36] f32
    __shared__ __align__(16) u16   as_[8 * 4 * 32]; // 2048 B,  [i][l][32 j]
    __shared__ __align__(16) float v1s[8 * 4 * 32]; // 4096 B,  [i][l][32 d]
    int bh = blockIdx.x;
    int i0 = blockIdx.y * 8;
    int jh = blockIdx.z;                               // j-half
    int bl = bh >> 2, h = bh & 3;
    int tid = threadIdx.x;
    int j32 = tid & 31;
    int ih = (tid >> 5) & 1;                           // i-half within block
    int dh = (tid >> 6) * 8;                           // d-chunk base (wave id)
    int jg = jh * 32 + j32;                            // global j
    const u16*   v2base = v2b + (size_t)bh * 131072;
    const float* v1base = v1f + (size_t)bh * 131072 + (size_t)i0 * 2048;
    const u16*   abase  = a + (size_t)bh * 262144 + (size_t)i0 * 4096;

    // load-index precompute
    int lz[2], jz[2], cz[2];
    #pragma unroll
    for (int it = 0; it < 2; ++it) {
        int idx = tid + it * 256;            // [0,512) uint4s for v2 (4l x 32j x 4)
        lz[it] = idx >> 7; jz[it] = (idx >> 2) & 31; cz[it] = idx & 3;
    }
    int ia = tid >> 5, la = (tid >> 3) & 3, jaq = tid & 7;         // a: uint2/thread
    int iv = tid >> 5, lv = (tid >> 3) & 3, dvq = (tid & 7) * 4;   // v1: f32x4/thread

    uint4 pv2[2]; uint2 pa; f32x4 pv1;

#define LOAD_CHUNK(l0_)                                                             \
    _Pragma("unroll")                                                               \
    for (int it = 0; it < 2; ++it)                                                  \
        pv2[it] = *(const uint4*)(v2base + ((size_t)((l0_) + lz[it]) * 64 + jh * 32 + jz[it]) * 32 + cz[it] * 8); \
    pa  = *(const uint2*)(abase + (size_t)ia * 4096 + ((l0_) + la) * 64 + jh * 32 + jaq * 4); \
    pv1 = *(const f32x4*)(v1base + (size_t)iv * 2048 + ((l0_) + lv) * 32 + dvq);

#define STORE_CHUNK()                                                               \
    _Pragma("unroll")                                                               \
    for (int it = 0; it < 2; ++it) {                                                \
        const u16* ds = (const u16*)&pv2[it];                                       \
        float* dst = &v2s[lz[it] * 1152 + jz[it] * 36 + cz[it] * 8];                \
        _Pragma("unroll")                                                           \
        for (int e = 0; e < 8; e++) dst[e] = b2f(ds[e]);                            \
    }                                                                               \
    *(uint2*)&as_[ia * 128 + la * 32 + jaq * 4] = pa;                               \
    *(f32x4*)&v1s[iv * 128 + lv * 32 + dvq] = pv1;

    float acc[4][8];
    float Z[4];
    #pragma unroll
    for (int i = 0; i < 4; i++) {
        Z[i] = 0.f;
        #pragma unroll
        for (int e = 0; e < 8; e++) acc[i][e] = 0.f;
    }

    LOAD_CHUNK(0);
    for (int ch = 0; ch < 16; ++ch) {
        if (ch) __syncthreads();             // previous chunk's readers done
        STORE_CHUNK();
        if (ch + 1 < 16) LOAD_CHUNK((ch + 1) * 4);
        __syncthreads();
        #pragma unroll
        for (int lc = 0; lc < 4; ++lc) {
            const float* vp = &v2s[lc * 1152 + j32 * 36 + dh];
            float v2r[8];
            *(f32x4*)&v2r[0] = *(const f32x4*)vp;
            *(f32x4*)&v2r[4] = *(const f32x4*)(vp + 4);
            #pragma unroll
            for (int ii = 0; ii < 4; ++ii) {
                int iL = ih * 4 + ii;
                float sv = b2f(as_[iL * 128 + lc * 32 + j32]);
                float av = __expf(sv);
                Z[ii] += av;
                const float* v1p = &v1s[iL * 128 + lc * 32 + dh];   // broadcast reads
                #pragma unroll
                for (int e = 0; e < 8; e++)
                    acc[ii][e] += (av * v1p[e]) * v2r[e];
            }
        }
    }
#undef LOAD_CHUNK
#undef STORE_CHUNK

    #pragma unroll
    for (int ii = 0; ii < 4; ++ii) {
        int iL = ih * 4 + ii;
        float sc = 1.0f / Z[ii];
        u16 tmp[8];
        #pragma unroll
        for (int e = 0; e < 8; e++) tmp[e] = f2b(acc[ii][e] * sc);
        *(uint4*)(ob + ((size_t)(bl * 64 + i0 + iL) * 64 + jg) * 128 + h * 32 + dh) = *(uint4*)tmp;
    }
}

// ---------------------------------------------------------------- final diag head (fp32 out)
__global__ __launch_bounds__(256) void out_kernel(
    const float* __restrict__ tokf, const u16* __restrict__ Wout, const u16* __restrict__ bout,
    float* __restrict__ out)
{
    int g = blockIdx.x * 256 + threadIdx.x;   // [0,512)
    int b = g >> 6, i = g & 63;
    const float* p = tokf + ((size_t)(b * 64 + i) * 64 + i) * 128;
    float s = b2f(bout[0]);
    #pragma unroll
    for (int d = 0; d < 128; d++) s += p[d] * b2f(Wout[d]);
    out[g] = s;
}

// ---------------------------------------------------------------- launch
extern "C" void kernel_launch(void* const* d_in, const int* in_sizes, int n_in,
                              void* d_out, int out_size, void* d_ws, size_t ws_size,
                              hipStream_t stream) {
    const void* mask = d_in[2];
    ParamPtrs pp;
    for (int k = 0; k < NSEG; ++k) pp.p[k] = d_in[k < 2 ? k : k + 1];   // skip mask

    char* ws = (char*)d_ws;
    u16* arena = (u16*)ws;
    #define AP(k) ((const u16*)ws + h_seg_off[k])
    int*   mmode = (int*)(ws + 1835008);
    float* tokf  = (float*)(ws + 2097152);      // 16 MB
    u16*   tokb  = (u16*)(ws + 18874368);       //  8 MB
    const size_t base = 27262976;
    const size_t MB = 1048576ULL;

    // adaptive splits vs ws_size: attn needs base + 7*NB MB
    int NB = 8;
    while (NB > 1 && base + (size_t)NB * 7 * MB > ws_size) NB >>= 1;

    u16*   qb  = (u16*)(ws + base);                       // NB MB
    u16*   kb  = (u16*)(ws + base + (size_t)NB * MB);     // NB MB
    u16*   v2b = (u16*)(ws + base + (size_t)NB * 2 * MB); // NB MB
    float* v1f = (float*)(ws + base + (size_t)NB * 3 * MB); // 2*NB MB
    u16*   sb  = (u16*)(ws + base + (size_t)NB * 5 * MB);   // 2*NB MB
    u16*   ob  = qb;                              // q dead after attn_s

    convert_params<<<1024, 256, 0, stream>>>(pp, arena, mask, mmode);
    assemble_kernel<<<4096, 256, 0, stream>>>(AP(0), AP(1), mask, mmode,
                                              AP(2), AP(3), AP(4), AP(5), AP(6), tokf, tokb);

    for (int l = 0; l < 3; ++l) {
        const u16* Wq_l  = AP(7)  + l * 16384;
        const u16* Wk_l  = AP(8)  + l * 16384;
        const u16* Wv1_l = AP(9)  + l * 16384;
        const u16* Wv2_l = AP(10) + l * 16384;
        const u16* Wo_l  = AP(11) + l * 16384;
        const u16* bo_l  = AP(12) + l * 128;
        const u16* g1_l  = AP(13) + l * 128;
        const u16* be1_l = AP(14) + l * 128;
        const u16* W1_l  = AP(15) + l * 65536;
        const u16* b1_l  = AP(16) + l * 512;
        const u16* W2_l  = AP(17) + l * 65536;
        const u16* b2_l  = AP(18) + l * 128;
        const u16* g2_l  = AP(19) + l * 128;
        const u16* be2_l = AP(20) + l * 128;

        for (int r = 0; r < 8 / NB; ++r) {
            size_t rowOff = (size_t)r * NB * 4096;
            gemm_qkv_kernel<<<dim3(NB * 32, 4), 256, 0, stream>>>(
                tokb + rowOff * 128, Wq_l, Wk_l, Wv1_l, Wv2_l,
                v1f, qb, kb, v2b);
            attn_s_kernel<<<NB * 256, 64, 0, stream>>>(qb, kb, sb);
            attn_o_kernel<<<dim3(NB * 4, 8, 2), 256, 0, stream>>>(sb, v1f, v2b, ob);
            fuse2_kernel<<<NB * 64, 256, 0, stream>>>(
                ob, Wo_l, bo_l, g1_l, be1_l, W1_l, b1_l, W2_l, b2_l, g2_l, be2_l,
                tokf + rowOff * 128, tokb + rowOff * 128);
        }
    }
    out_kernel<<<2, 256, 0, stream>>>(tokf, AP(21), AP(22), (float*)d_out);
}

// Round 12
// 403.070 us; speedup vs baseline: 1.2182x; 1.2182x over previous
//
#include <hip/hip_runtime.h>

typedef unsigned short u16;
typedef __attribute__((ext_vector_type(8))) short bf16x8;
typedef __attribute__((ext_vector_type(4))) float f32x4;

#define INV_SCALE 0.17677669529663687f

static __device__ __forceinline__ float b2f(u16 u) {
    union { unsigned int i; float f; } v; v.i = ((unsigned int)u) << 16; return v.f;
}
static __device__ __forceinline__ u16 f2b(float f) {
    union { float f; unsigned int i; } v; v.f = f;
    unsigned int r = (v.i + 0x7FFFu + ((v.i >> 16) & 1u)) >> 16;
    return (u16)r;
}

// ---- param arena segment table (bf16 elements), shared host/device ----
// Weight segs 7-11 (128x128/layer), 15 (W1), 17 (W2) are stored TRANSPOSED [n][k].
#define NSEG 23
__device__ __constant__ int d_seg_off[NSEG + 1] = {
    0, 8192, 270336, 272384, 272512, 273536, 273664, 273792, 322944, 372096,
    421248, 470400, 519552, 519936, 520320, 520704, 717312, 718848, 915456,
    915840, 916224, 916608, 916736, 916744};
static const int h_seg_off[NSEG + 1] = {
    0, 8192, 270336, 272384, 272512, 273536, 273664, 273792, 322944, 372096,
    421248, 470400, 519552, 519936, 520320, 520704, 717312, 718848, 915456,
    915840, 916224, 916608, 916736, 916744};
#define ARENA_TOTAL 916744

struct ParamPtrs { const void* p[NSEG]; };

// ---------------------------------------------------------------- param convert + mask probe
__global__ __launch_bounds__(256) void convert_params(ParamPtrs pp, u16* __restrict__ arena,
                                                      const void* __restrict__ mask,
                                                      int* __restrict__ mode) {
    if (blockIdx.x == 0) {
        __shared__ int f16, f32s, u8s;
        int tid = threadIdx.x;
        if (tid == 0) { f16 = 0; f32s = 0; u8s = 0; }
        __syncthreads();
        const u16* mu = (const u16*)mask;
        const unsigned int* mw = (const unsigned int*)mask;
        if (mu[2 * tid] == 0x3F80u) atomicOr(&f16, 1);
        if (mw[tid] == 0x3F800000u) atomicOr(&f32s, 1);
        if (mw[tid] > 1u) atomicOr(&u8s, 1);
        __syncthreads();
        if (tid == 0) mode[0] = f16 ? 0 : (f32s ? 3 : (u8s ? 1 : 2));
    }
    const unsigned int probe = ((const unsigned int*)pp.p[13])[0];   // ln1_g[0] == 1.0
    const bool f32 = (probe == 0x3F800000u);
    for (int e = blockIdx.x * 256 + threadIdx.x; e < ARENA_TOTAL; e += gridDim.x * 256) {
        int k = 0;
        #pragma unroll
        for (int s2 = 1; s2 < NSEG; ++s2) if (e >= d_seg_off[s2]) k = s2;
        int local = e - d_seg_off[k];
        // transposed weight segments: arena [l][n][k] <- src [l][k][n]
        int src = local;
        if (k >= 7 && k <= 11) {                 // [L][128k][128n] -> [L][128n][128k]
            int l = local >> 14, rem = local & 16383;
            int n = rem >> 7, kk = rem & 127;
            src = (l << 14) + kk * 128 + n;
        } else if (k == 15) {                    // W1 [L][128k][512n] -> [L][512n][128k]
            int l = local >> 16, rem = local & 65535;
            int n = rem >> 7, kk = rem & 127;
            src = (l << 16) + kk * 512 + n;
        } else if (k == 17) {                    // W2 [L][512k][128n] -> [L][128n][512k]
            int l = local >> 16, rem = local & 65535;
            int n = rem >> 9, kk = rem & 511;
            src = (l << 16) + kk * 128 + n;
        }
        u16 v;
        if (k == 22 && local >= 1) v = 0;   // bout padded 1 -> 8
        else v = f32 ? f2b(((const float*)pp.p[k])[src]) : ((const u16*)pp.p[k])[src];
        arena[e] = v;
    }
}

// ---------------------------------------------------------------- tok assembly (mask fused)
__global__ __launch_bounds__(256) void assemble_kernel(
    const u16* __restrict__ x, const u16* __restrict__ ea,
    const void* __restrict__ mask, const int* __restrict__ modeptr,
    const u16* __restrict__ nodeW, const u16* __restrict__ nodeB,
    const u16* __restrict__ edgeW, const u16* __restrict__ edgeB, const u16* __restrict__ noedge,
    float* __restrict__ tokf, u16* __restrict__ tokb)
{
    const int md = modeptr[0];
    int g = blockIdx.x * 256 + threadIdx.x;      // [0, 1048576)
    int t = g >> 5, dq = g & 31, d0 = dq * 4;
    int b = t >> 12, i = (t >> 6) & 63, j = t & 63;
    float v[4];
    if (i == j) {
        #pragma unroll
        for (int c = 0; c < 4; c++) v[c] = b2f(nodeB[d0 + c]);
        #pragma unroll
        for (int e = 0; e < 16; e++) {
            float xe = b2f(x[(b * 64 + i) * 16 + e]);
            #pragma unroll
            for (int c = 0; c < 4; c++) v[c] += xe * b2f(nodeW[e * 128 + d0 + c]);
        }
    } else {
        bool edge;
        if (md == 0)      edge = ((const u16*)mask)[t] != 0;
        else if (md == 3) edge = ((const float*)mask)[t] != 0.0f;
        else if (md == 1) edge = ((const unsigned char*)mask)[t] != 0;
        else              edge = ((const unsigned int*)mask)[t] != 0;
        if (edge) {
            #pragma unroll
            for (int c = 0; c < 4; c++) v[c] = b2f(edgeB[d0 + c]);
            #pragma unroll
            for (int e = 0; e < 8; e++) {
                float ae = b2f(ea[t * 8 + e]);
                #pragma unroll
                for (int c = 0; c < 4; c++) v[c] += ae * b2f(edgeW[e * 128 + d0 + c]);
            }
        } else {
            #pragma unroll
            for (int c = 0; c < 4; c++) v[c] = b2f(noedge[d0 + c]);
        }
    }
    *(float4*)(tokf + (size_t)t * 128 + d0) = make_float4(v[0], v[1], v[2], v[3]);
    u16 pk[4];
    #pragma unroll
    for (int c = 0; c < 4; c++) pk[c] = f2b(v[c]);
    *(uint2*)(tokb + (size_t)t * 128 + d0) = *(uint2*)pk;
}

// ---------------------------------------------------------------- generic GEMM (512 thr, 8 waves, BM=128)
// B TRANSPOSED [n][128]; vector uint4 staging. modes: 3=qkv scatter (by==2 -> fp32 v1f),
//        4=bias+residual+LayerNorm fused -> tokf(fp32) + tokbO(bf16)
__global__ __launch_bounds__(512) void gemm_kernel(
    const u16* __restrict__ A, int lda,
    const u16* __restrict__ B0, const u16* __restrict__ B1,
    const u16* __restrict__ B2, const u16* __restrict__ B3,
    int ldbt, const u16* __restrict__ bias,
    int K, int mode,
    u16* __restrict__ outb, int ldc,
    float* __restrict__ tokf,
    u16* __restrict__ qb, u16* __restrict__ kb, u16* __restrict__ v2b,
    const u16* __restrict__ lng, const u16* __restrict__ lnb, u16* __restrict__ tokbO)
{
    __shared__ __align__(16) u16 smem[2 * 128 * 72];   // 36864 B
    u16* As = smem;
    u16* Bs = smem + 128 * 72;
    int tid = threadIdx.x;
    int m0 = blockIdx.x * 128;
    int by = blockIdx.y;
    const u16* Bp;
    if (mode == 3) { Bp = (by == 0) ? B0 : (by == 1) ? B1 : (by == 2) ? B2 : B3; }
    else { Bp = B0; }

    int w = tid >> 6, lane = tid & 63;
    int q = lane >> 4, r16 = lane & 15;
    int rw = (w >> 1) * 32, cw = (w & 1) * 64;

    f32x4 acc[2][4];
    #pragma unroll
    for (int mi = 0; mi < 2; mi++)
        #pragma unroll
        for (int ni = 0; ni < 4; ni++) acc[mi][ni] = (f32x4){0.f, 0.f, 0.f, 0.f};

    int nkt = K >> 6;
    for (int kt = 0; kt < nkt; ++kt) {
        int k0 = kt * 64;
        __syncthreads();
        #pragma unroll
        for (int it = 0; it < 2; ++it) {               // A: 128 x 64 (1024 uint4)
            int idx = tid + it * 512;
            int row = idx >> 3, ch = idx & 7;
            uint4 d = *(const uint4*)(A + (size_t)(m0 + row) * lda + k0 + ch * 8);
            *(uint4*)&As[row * 72 + ch * 8] = d;
        }
        #pragma unroll
        for (int it = 0; it < 2; ++it) {               // B^T: 128 n x 64 k (1024 uint4, vector)
            int idx = tid + it * 512;
            int n = idx >> 3, ch = idx & 7;
            uint4 d = *(const uint4*)(Bp + (size_t)n * ldbt + k0 + ch * 8);
            int ch2 = ch ^ ((n >> 3) & 7);
            *(uint4*)&Bs[n * 72 + ch2 * 8] = d;
        }
        __syncthreads();
        #pragma unroll
        for (int ks = 0; ks < 2; ++ks) {
            bf16x8 fa[2], fb[4];
            #pragma unroll
            for (int mi = 0; mi < 2; mi++)
                fa[mi] = *(const bf16x8*)&As[(rw + mi * 16 + r16) * 72 + ks * 32 + q * 8];
            #pragma unroll
            for (int ni = 0; ni < 4; ni++) {
                int n = cw + ni * 16 + r16;
                int ch2 = (ks * 4 + q) ^ ((n >> 3) & 7);
                fb[ni] = *(const bf16x8*)&Bs[n * 72 + ch2 * 8];
            }
            #pragma unroll
            for (int mi = 0; mi < 2; mi++)
                #pragma unroll
                for (int ni = 0; ni < 4; ni++)
                    acc[mi][ni] = __builtin_amdgcn_mfma_f32_16x16x32_bf16(fa[mi], fb[ni], acc[mi][ni], 0, 0, 0);
        }
    }

    // ---------------- epilogue ----------------
    int bl = m0 >> 12, it0 = (m0 >> 6) & 63;
    __syncthreads();
    if (mode == 4) {
        // ---- bias + residual + LayerNorm fused, write tokf (fp32) + tokbO (bf16) ----
        float* cf  = (float*)smem;                 // [128][64] fp32, XOR-swizzled (32 KB)
        float* rsm = cf + 128 * 64;                // [2][128] half row sums   (1 KB)
        float* rqm = rsm + 256;                    // [2][128] half row sumsq  (1 KB)
        int half = cw >> 6;
        #pragma unroll
        for (int ni = 0; ni < 4; ni++) {
            int col = cw + ni * 16 + r16;
            float bb = b2f(bias[col]);
            #pragma unroll
            for (int mi = 0; mi < 2; mi++)
                #pragma unroll
                for (int rr = 0; rr < 4; rr++) {
                    int r = rw + mi * 16 + q * 4 + rr;
                    acc[mi][ni][rr] += bb + tokf[(size_t)(m0 + r) * 128 + col];
                }
        }
        #pragma unroll
        for (int mi = 0; mi < 2; mi++)
            #pragma unroll
            for (int rr = 0; rr < 4; rr++) {
                float s = 0.f, sq = 0.f;
                #pragma unroll
                for (int ni = 0; ni < 4; ni++) { float t = acc[mi][ni][rr]; s += t; sq += t * t; }
                #pragma unroll
                for (int off = 1; off < 16; off <<= 1) {
                    s  += __shfl_xor(s,  off, 16);
                    sq += __shfl_xor(sq, off, 16);
                }
                if (r16 == 0) {
                    int r = rw + mi * 16 + q * 4 + rr;
                    rsm[half * 128 + r] = s;
                    rqm[half * 128 + r] = sq;
                }
            }
        __syncthreads();
        float gl[4], bv[4];
        #pragma unroll
        for (int ni = 0; ni < 4; ni++) {
            int col = cw + ni * 16 + r16;
            gl[ni] = b2f(lng[col]);
            bv[ni] = b2f(lnb[col]);
        }
        #pragma unroll
        for (int mi = 0; mi < 2; mi++)
            #pragma unroll
            for (int rr = 0; rr < 4; rr++) {
                int r = rw + mi * 16 + q * 4 + rr;
                float tot = rsm[r] + rsm[128 + r];
                float tq  = rqm[r] + rqm[128 + r];
                float mean = tot * 0.0078125f;
                float var  = tq * 0.0078125f - mean * mean;
                float rstd = rsqrtf(var + 1e-5f);
                #pragma unroll
                for (int ni = 0; ni < 4; ni++)
                    acc[mi][ni][rr] = (acc[mi][ni][rr] - mean) * rstd * gl[ni] + bv[ni];
            }
        #pragma unroll
        for (int hp = 0; hp < 2; ++hp) {
            __syncthreads();
            if (half == hp) {
                #pragma unroll
                for (int mi = 0; mi < 2; mi++)
                    #pragma unroll
                    for (int ni = 0; ni < 4; ni++) {
                        int colh = (cw & 63) + ni * 16 + r16;
                        int ch4 = colh >> 2, cl = colh & 3;
                        #pragma unroll
                        for (int rr = 0; rr < 4; rr++) {
                            int r = rw + mi * 16 + q * 4 + rr;
                            cf[r * 64 + (((ch4 ^ (r & 15)) << 2) | cl)] = acc[mi][ni][rr];
                        }
                    }
            }
            __syncthreads();
            #pragma unroll
            for (int it = 0; it < 4; ++it) {
                int idx = tid + it * 512;              // (r:7 | c4:4)
                int r = idx >> 4, c4 = idx & 15;
                f32x4 v = *(const f32x4*)&cf[r * 64 + ((c4 ^ (r & 15)) << 2)];
                int col = hp * 64 + c4 * 4;
                *(f32x4*)(tokf + (size_t)(m0 + r) * 128 + col) = v;
                u16 pk[4];
                #pragma unroll
                for (int e = 0; e < 4; e++) pk[e] = f2b(v[e]);
                *(uint2*)(tokbO + (size_t)(m0 + r) * 128 + col) = *(uint2*)pk;
            }
        }
    } else if (mode == 3 && by == 2) {
        // ---- v1f fp32 scatter: [bh][i=it][l=jt][32] ----
        float* cf = (float*)smem;                      // [128][64] fp32, XOR-swizzled
        #pragma unroll
        for (int hp = 0; hp < 2; ++hp) {
            if (hp) __syncthreads();
            if ((cw >> 6) == hp) {
                #pragma unroll
                for (int mi = 0; mi < 2; mi++) {
                    #pragma unroll
                    for (int ni = 0; ni < 4; ni++) {
                        int colh = (cw & 63) + ni * 16 + r16;
                        int ch4 = colh >> 2, cl = colh & 3;
                        #pragma unroll
                        for (int rr = 0; rr < 4; rr++) {
                            int r = rw + mi * 16 + q * 4 + rr;
                            cf[r * 64 + (((ch4 ^ (r & 15)) << 2) | cl)] = acc[mi][ni][rr];
                        }
                    }
                }
            }
            __syncthreads();
            #pragma unroll
            for (int it = 0; it < 4; ++it) {
                int idx = tid + it * 512;          // (hh:1 | itl:1 | jt:6 | d4:3)
                int hh = idx >> 10, itl = (idx >> 9) & 1, jt = (idx >> 3) & 63, d4 = idx & 7;
                int r = itl * 64 + jt;
                int colh = hh * 32 + d4 * 4;
                f32x4 v = *(const f32x4*)&cf[r * 64 + (((colh >> 2) ^ (r & 15)) << 2)];
                int h = hp * 2 + hh;
                *(f32x4*)&tokf[((((size_t)(bl * 4 + h)) * 64 + it0 + itl) * 64 + jt) * 32 + d4 * 4] = v;
            }
        }
    } else {
        // ---- bf16 scatter paths: mode 3 by in {0,1,3} (q/k/v2) ----
        u16* cs = smem;                                // [128][128] u16, XOR-swizzled
        #pragma unroll
        for (int mi = 0; mi < 2; mi++) {
            #pragma unroll
            for (int ni = 0; ni < 4; ni++) {
                int col = cw + ni * 16 + r16;
                int ch = col >> 3, cl = col & 7;
                #pragma unroll
                for (int rr = 0; rr < 4; rr++) {
                    int r = rw + mi * 16 + q * 4 + rr;
                    cs[r * 128 + (((ch ^ (r & 15)) << 3) | cl)] = f2b(acc[mi][ni][rr]);
                }
            }
        }
        __syncthreads();
        if (by == 0) {                                 // q: [bh][l=jt][i=it][32]
            #pragma unroll
            for (int it = 0; it < 4; ++it) {
                int idx = tid + it * 512;              // (h:2 | jt:6 | itl:1 | d8:2)
                int h = idx >> 9, jt = (idx >> 3) & 63, itl = (idx >> 2) & 1, d8 = idx & 3;
                int r = itl * 64 + jt, c8 = h * 4 + d8;
                uint4 d = *(const uint4*)&cs[r * 128 + ((c8 ^ (r & 15)) << 3)];
                *(uint4*)&qb[((((size_t)(bl * 4 + h)) * 64 + jt) * 64 + it0 + itl) * 32 + d8 * 8] = d;
            }
        } else {                                       // k / v2: [bh][i=it][j=jt][32]
            u16* dp = (by == 1) ? kb : v2b;
            #pragma unroll
            for (int it = 0; it < 4; ++it) {
                int idx = tid + it * 512;              // (h:2 | itl:1 | jt:6 | d8:2)
                int h = idx >> 9, itl = (idx >> 8) & 1, jt = (idx >> 2) & 63, d8 = idx & 3;
                int r = itl * 64 + jt, c8 = h * 4 + d8;
                uint4 d = *(const uint4*)&cs[r * 128 + ((c8 ^ (r & 15)) << 3)];
                *(uint4*)&dp[((((size_t)(bl * 4 + h)) * 64 + it0 + itl) * 64 + jt) * 32 + d8 * 8] = d;
            }
        }
    }
}

// ---------------------------------------------------------------- fused FF (512 thr, 8 waves, BM=128)
// W1T [512 n][128 k], W2T [128 n][512 k]; vector uint4 B-staging.
__global__ __launch_bounds__(512) void ff_kernel(
    const u16* __restrict__ A,                     // tokb (bf16, post-LN1)
    const u16* __restrict__ W1T, const u16* __restrict__ b1,
    const u16* __restrict__ W2T, const u16* __restrict__ b2,
    const u16* __restrict__ lng, const u16* __restrict__ lnb,
    float* __restrict__ tokf, u16* __restrict__ tokbO)
{
    __shared__ __align__(16) u16 smem[2 * 128 * 72];   // 36864 B
    u16* As = smem;
    u16* Bs = smem + 128 * 72;
    int tid = threadIdx.x;
    int m0 = blockIdx.x * 128;
    int w = tid >> 6, lane = tid & 63;
    int q = lane >> 4, r16 = lane & 15;
    int rw = (w >> 1) * 32, cw = (w & 1) * 64;

    f32x4 acc2[2][4];
    #pragma unroll
    for (int mi = 0; mi < 2; mi++)
        #pragma unroll
        for (int ni = 0; ni < 4; ni++) acc2[mi][ni] = (f32x4){0.f, 0.f, 0.f, 0.f};

    for (int hs = 0; hs < 4; ++hs) {
        f32x4 acc1[2][4];
        #pragma unroll
        for (int mi = 0; mi < 2; mi++)
            #pragma unroll
            for (int ni = 0; ni < 4; ni++) acc1[mi][ni] = (f32x4){0.f, 0.f, 0.f, 0.f};
        #pragma unroll
        for (int kt = 0; kt < 2; ++kt) {
            int k0 = kt * 64;
            __syncthreads();
            #pragma unroll
            for (int it = 0; it < 2; ++it) {           // A: 128 x 64 (tokb, L2-hot re-stage)
                int idx = tid + it * 512;
                int row = idx >> 3, ch = idx & 7;
                uint4 d = *(const uint4*)(A + (size_t)(m0 + row) * 128 + k0 + ch * 8);
                *(uint4*)&As[row * 72 + ch * 8] = d;
            }
            #pragma unroll
            for (int it = 0; it < 2; ++it) {           // B: W1T rows hs*128.. (vector)
                int idx = tid + it * 512;
                int n = idx >> 3, ch = idx & 7;
                uint4 d = *(const uint4*)(W1T + (size_t)(hs * 128 + n) * 128 + k0 + ch * 8);
                int ch2 = ch ^ ((n >> 3) & 7);
                *(uint4*)&Bs[n * 72 + ch2 * 8] = d;
            }
            __syncthreads();
            #pragma unroll
            for (int ks = 0; ks < 2; ++ks) {
                bf16x8 fa[2], fb[4];
                #pragma unroll
                for (int mi = 0; mi < 2; mi++)
                    fa[mi] = *(const bf16x8*)&As[(rw + mi * 16 + r16) * 72 + ks * 32 + q * 8];
                #pragma unroll
                for (int ni = 0; ni < 4; ni++) {
                    int n = cw + ni * 16 + r16;
                    int ch2 = (ks * 4 + q) ^ ((n >> 3) & 7);
                    fb[ni] = *(const bf16x8*)&Bs[n * 72 + ch2 * 8];
                }
                #pragma unroll
                for (int mi = 0; mi < 2; mi++)
                    #pragma unroll
                    for (int ni = 0; ni < 4; ni++)
                        acc1[mi][ni] = __builtin_amdgcn_mfma_f32_16x16x32_bf16(fa[mi], fb[ni], acc1[mi][ni], 0, 0, 0);
            }
        }
        #pragma unroll
        for (int half = 0; half < 2; ++half) {
            __syncthreads();
            if ((w & 1) == half) {                     // 4 waves own these 64 hidden cols
                #pragma unroll
                for (int mi = 0; mi < 2; mi++)
                    #pragma unroll
                    for (int ni = 0; ni < 4; ni++) {
                        int kl = ni * 16 + r16;
                        float bb = b2f(b1[hs * 128 + half * 64 + kl]);
                        #pragma unroll
                        for (int rr = 0; rr < 4; rr++) {
                            int row = rw + mi * 16 + q * 4 + rr;
                            As[row * 72 + kl] = f2b(fmaxf(acc1[mi][ni][rr] + bb, 0.f));
                        }
                    }
            }
            #pragma unroll
            for (int it = 0; it < 2; ++it) {           // B: W2T [n][512], k-slice hs*128+half*64
                int idx = tid + it * 512;
                int n = idx >> 3, ch = idx & 7;
                uint4 d = *(const uint4*)(W2T + (size_t)n * 512 + hs * 128 + half * 64 + ch * 8);
                int ch2 = ch ^ ((n >> 3) & 7);
                *(uint4*)&Bs[n * 72 + ch2 * 8] = d;
            }
            __syncthreads();
            #pragma unroll
            for (int ks = 0; ks < 2; ++ks) {
                bf16x8 fa[2], fb[4];
                #pragma unroll
                for (int mi = 0; mi < 2; mi++)
                    fa[mi] = *(const bf16x8*)&As[(rw + mi * 16 + r16) * 72 + ks * 32 + q * 8];
                #pragma unroll
                for (int ni = 0; ni < 4; ni++) {
                    int n = cw + ni * 16 + r16;
                    int ch2 = (ks * 4 + q) ^ ((n >> 3) & 7);
                    fb[ni] = *(const bf16x8*)&Bs[n * 72 + ch2 * 8];
                }
                #pragma unroll
                for (int mi = 0; mi < 2; mi++)
                    #pragma unroll
                    for (int ni = 0; ni < 4; ni++)
                        acc2[mi][ni] = __builtin_amdgcn_mfma_f32_16x16x32_bf16(fa[mi], fb[ni], acc2[mi][ni], 0, 0, 0);
            }
        }
    }

    // ---- epilogue: bias b2 + residual tokf + LayerNorm -> tokf + tokbO ----
    __syncthreads();
    float* cf  = (float*)smem;
    float* rsm = cf + 128 * 64;
    float* rqm = rsm + 256;
    int half = cw >> 6;
    #pragma unroll
    for (int ni = 0; ni < 4; ni++) {
        int col = cw + ni * 16 + r16;
        float bb = b2f(b2[col]);
        #pragma unroll
        for (int mi = 0; mi < 2; mi++)
            #pragma unroll
            for (int rr = 0; rr < 4; rr++) {
                int r = rw + mi * 16 + q * 4 + rr;
                acc2[mi][ni][rr] += bb + tokf[(size_t)(m0 + r) * 128 + col];
            }
    }
    #pragma unroll
    for (int mi = 0; mi < 2; mi++)
        #pragma unroll
        for (int rr = 0; rr < 4; rr++) {
            float s = 0.f, sq = 0.f;
            #pragma unroll
            for (int ni = 0; ni < 4; ni++) { float t = acc2[mi][ni][rr]; s += t; sq += t * t; }
            #pragma unroll
            for (int off = 1; off < 16; off <<= 1) {
                s  += __shfl_xor(s,  off, 16);
                sq += __shfl_xor(sq, off, 16);
            }
            if (r16 == 0) {
                int r = rw + mi * 16 + q * 4 + rr;
                rsm[half * 128 + r] = s;
                rqm[half * 128 + r] = sq;
            }
        }
    __syncthreads();
    float gl[4], bv[4];
    #pragma unroll
    for (int ni = 0; ni < 4; ni++) {
        int col = cw + ni * 16 + r16;
        gl[ni] = b2f(lng[col]);
        bv[ni] = b2f(lnb[col]);
    }
    #pragma unroll
    for (int mi = 0; mi < 2; mi++)
        #pragma unroll
        for (int rr = 0; rr < 4; rr++) {
            int r = rw + mi * 16 + q * 4 + rr;
            float tot = rsm[r] + rsm[128 + r];
            float tq  = rqm[r] + rqm[128 + r];
            float mean = tot * 0.0078125f;
            float var  = tq * 0.0078125f - mean * mean;
            float rstd = rsqrtf(var + 1e-5f);
            #pragma unroll
            for (int ni = 0; ni < 4; ni++)
                acc2[mi][ni][rr] = (acc2[mi][ni][rr] - mean) * rstd * gl[ni] + bv[ni];
        }
    #pragma unroll
    for (int hp = 0; hp < 2; ++hp) {
        __syncthreads();
        if (half == hp) {
            #pragma unroll
            for (int mi = 0; mi < 2; mi++)
                #pragma unroll
                for (int ni = 0; ni < 4; ni++) {
                    int colh = (cw & 63) + ni * 16 + r16;
                    int ch4 = colh >> 2, cl = colh & 3;
                    #pragma unroll
                    for (int rr = 0; rr < 4; rr++) {
                        int r = rw + mi * 16 + q * 4 + rr;
                        cf[r * 64 + (((ch4 ^ (r & 15)) << 2) | cl)] = acc2[mi][ni][rr];
                    }
                }
        }
        __syncthreads();
        #pragma unroll
        for (int it = 0; it < 4; ++it) {
            int idx = tid + it * 512;              // (r:7 | c4:4)
            int r = idx >> 4, c4 = idx & 15;
            f32x4 v = *(const f32x4*)&cf[r * 64 + ((c4 ^ (r & 15)) << 2)];
            int col = hp * 64 + c4 * 4;
            *(f32x4*)(tokf + (size_t)(m0 + r) * 128 + col) = v;
            u16 pk[4];
            #pragma unroll
            for (int e = 0; e < 4; e++) pk[e] = f2b(v[e]);
            *(uint2*)(tokbO + (size_t)(m0 + r) * 128 + col) = *(uint2*)pk;
        }
    }
}

// ---------------------------------------------------------------- s = QK^T/scale (bf16 out, raw logits)
__global__ __launch_bounds__(64) void attn_s_kernel(
    const u16* __restrict__ qb, const u16* __restrict__ kb, u16* __restrict__ s)
{
    __shared__ __align__(16) u16 sm[64 * 80];          // qs(64x40) + ks(64x40); reused as cs(64x72)
    u16* qs  = sm;
    u16* ks_ = sm + 64 * 40;
    int g = blockIdx.x;
    int l = g & 63, bh = g >> 6;
    const u16* Q = qb + ((size_t)bh * 64 + l) * 2048;
    const u16* Kp = kb + ((size_t)bh * 64 + l) * 2048;
    int lane = threadIdx.x;
    #pragma unroll
    for (int it = 0; it < 4; ++it) {
        int idx = lane + it * 64;
        int row = idx >> 2, c4 = idx & 3;
        *(uint4*)&qs[row * 40 + c4 * 8] = *(const uint4*)(Q + row * 32 + c4 * 8);
        *(uint4*)&ks_[row * 40 + c4 * 8] = *(const uint4*)(Kp + row * 32 + c4 * 8);
    }
    __syncthreads();
    int q = lane >> 4, r16 = lane & 15;
    f32x4 acc[4][4];
    #pragma unroll
    for (int mi = 0; mi < 4; mi++)
        #pragma unroll
        for (int ni = 0; ni < 4; ni++) acc[mi][ni] = (f32x4){0.f, 0.f, 0.f, 0.f};
    bf16x8 fa[4], fb[4];
    #pragma unroll
    for (int mi = 0; mi < 4; mi++) fa[mi] = *(const bf16x8*)&qs[(mi * 16 + r16) * 40 + q * 8];
    #pragma unroll
    for (int ni = 0; ni < 4; ni++) fb[ni] = *(const bf16x8*)&ks_[(ni * 16 + r16) * 40 + q * 8];
    #pragma unroll
    for (int mi = 0; mi < 4; mi++)
        #pragma unroll
        for (int ni = 0; ni < 4; ni++)
            acc[mi][ni] = __builtin_amdgcn_mfma_f32_16x16x32_bf16(fa[mi], fb[ni], acc[mi][ni], 0, 0, 0);
    // stage C tile in LDS, then coalesced stores
    __syncthreads();
    u16* cs = sm;                                      // 64 x 72
    #pragma unroll
    for (int mi = 0; mi < 4; mi++)
        #pragma unroll
        for (int ni = 0; ni < 4; ni++)
            #pragma unroll
            for (int rr = 0; rr < 4; rr++)
                cs[(mi * 16 + q * 4 + rr) * 72 + ni * 16 + r16] = f2b(acc[mi][ni][rr] * INV_SCALE);
    __syncthreads();
    u16* sb = s + (size_t)bh * 262144 + l * 64;
    #pragma unroll
    for (int it = 0; it < 8; ++it) {
        int row = it * 8 + (lane >> 3);
        uint4 d = *(const uint4*)&cs[row * 72 + (lane & 7) * 8];
        *(uint4*)&sb[(size_t)row * 4096 + (lane & 7) * 8] = d;
    }
}

// ---------------------------------------------------------------- o = softmax_l(s) * v1 * v2  (softmax fused)
// block = (bh, 8-i-group, j-half), 256 threads (4 waves), grid NB*4 x 8 x 2 = 512 -> 2 blocks/CU.
__global__ __launch_bounds__(256) void attn_o_kernel(
    const u16* __restrict__ a, const float* __restrict__ v1f, const u16* __restrict__ v2b,
    u16* __restrict__ ob)
{
    __shared__ __align__(16) float v2s[4 * 1152];   // 18432 B, [l][32 j][36] f32
    __shared__ __align__(16) u16   as_[8 * 4 * 32]; // 2048 B,  [i][l][32 j]
    __shared__ __align__(16) float v1s[8 * 4 * 32]; // 4096 B,  [i][l][32 d]
    int bh = blockIdx.x;
    int i0 = blockIdx.y * 8;
    int jh = blockIdx.z;                               // j-half
    int bl = bh >> 2, h = bh & 3;
    int tid = threadIdx.x;
    int j32 = tid & 31;
    int ih = (tid >> 5) & 1;                           // i-half within block
    int dh = (tid >> 6) * 8;                           // d-chunk base (wave id)
    int jg = jh * 32 + j32;                            // global j
    const u16*   v2base = v2b + (size_t)bh * 131072;
    const float* v1base = v1f + (size_t)bh * 131072 + (size_t)i0 * 2048;
    const u16*   abase  = a + (size_t)bh * 262144 + (size_t)i0 * 4096;

    // load-index precompute
    int lz[2], jz[2], cz[2];
    #pragma unroll
    for (int it = 0; it < 2; ++it) {
        int idx = tid + it * 256;            // [0,512) uint4s for v2 (4l x 32j x 4)
        lz[it] = idx >> 7; jz[it] = (idx >> 2) & 31; cz[it] = idx & 3;
    }
    int ia = tid >> 5, la = (tid >> 3) & 3, jaq = tid & 7;         // a: uint2/thread
    int iv = tid >> 5, lv = (tid >> 3) & 3, dvq = (tid & 7) * 4;   // v1: f32x4/thread

    uint4 pv2[2]; uint2 pa; f32x4 pv1;

#define LOAD_CHUNK(l0_)                                                             \
    _Pragma("unroll")                                                               \
    for (int it = 0; it < 2; ++it)                                                  \
        pv2[it] = *(const uint4*)(v2base + ((size_t)((l0_) + lz[it]) * 64 + jh * 32 + jz[it]) * 32 + cz[it] * 8); \
    pa  = *(const uint2*)(abase + (size_t)ia * 4096 + ((l0_) + la) * 64 + jh * 32 + jaq * 4); \
    pv1 = *(const f32x4*)(v1base + (size_t)iv * 2048 + ((l0_) + lv) * 32 + dvq);

#define STORE_CHUNK()                                                               \
    _Pragma("unroll")                                                               \
    for (int it = 0; it < 2; ++it) {                                                \
        const u16* ds = (const u16*)&pv2[it];                                       \
        float* dst = &v2s[lz[it] * 1152 + jz[it] * 36 + cz[it] * 8];                \
        _Pragma("unroll")                                                           \
        for (int e = 0; e < 8; e++) dst[e] = b2f(ds[e]);                            \
    }                                                                               \
    *(uint2*)&as_[ia * 128 + la * 32 + jaq * 4] = pa;                               \
    *(f32x4*)&v1s[iv * 128 + lv * 32 + dvq] = pv1;

    float acc[4][8];
    float Z[4];
    #pragma unroll
    for (int i = 0; i < 4; i++) {
        Z[i] = 0.f;
        #pragma unroll
        for (int e = 0; e < 8; e++) acc[i][e] = 0.f;
    }

    LOAD_CHUNK(0);
    for (int ch = 0; ch < 16; ++ch) {
        if (ch) __syncthreads();             // previous chunk's readers done
        STORE_CHUNK();
        if (ch + 1 < 16) LOAD_CHUNK((ch + 1) * 4);
        __syncthreads();
        #pragma unroll
        for (int lc = 0; lc < 4; ++lc) {
            const float* vp = &v2s[lc * 1152 + j32 * 36 + dh];
            float v2r[8];
            *(f32x4*)&v2r[0] = *(const f32x4*)vp;
            *(f32x4*)&v2r[4] = *(const f32x4*)(vp + 4);
            #pragma unroll
            for (int ii = 0; ii < 4; ++ii) {
                int iL = ih * 4 + ii;
                float sv = b2f(as_[iL * 128 + lc * 32 + j32]);
                float av = __expf(sv);
                Z[ii] += av;
                const float* v1p = &v1s[iL * 128 + lc * 32 + dh];   // broadcast reads
                #pragma unroll
                for (int e = 0; e < 8; e++)
                    acc[ii][e] += (av * v1p[e]) * v2r[e];
            }
        }
    }
#undef LOAD_CHUNK
#undef STORE_CHUNK

    #pragma unroll
    for (int ii = 0; ii < 4; ++ii) {
        int iL = ih * 4 + ii;
        float sc = 1.0f / Z[ii];
        u16 tmp[8];
        #pragma unroll
        for (int e = 0; e < 8; e++) tmp[e] = f2b(acc[ii][e] * sc);
        *(uint4*)(ob + ((size_t)(bl * 64 + i0 + iL) * 64 + jg) * 128 + h * 32 + dh) = *(uint4*)tmp;
    }
}

// ---------------------------------------------------------------- final diag head (fp32 out)
__global__ __launch_bounds__(256) void out_kernel(
    const float* __restrict__ tokf, const u16* __restrict__ Wout, const u16* __restrict__ bout,
    float* __restrict__ out)
{
    int g = blockIdx.x * 256 + threadIdx.x;   // [0,512)
    int b = g >> 6, i = g & 63;
    const float* p = tokf + ((size_t)(b * 64 + i) * 64 + i) * 128;
    float s = b2f(bout[0]);
    #pragma unroll
    for (int d = 0; d < 128; d++) s += p[d] * b2f(Wout[d]);
    out[g] = s;
}

// ---------------------------------------------------------------- launch
extern "C" void kernel_launch(void* const* d_in, const int* in_sizes, int n_in,
                              void* d_out, int out_size, void* d_ws, size_t ws_size,
                              hipStream_t stream) {
    const void* mask = d_in[2];
    ParamPtrs pp;
    for (int k = 0; k < NSEG; ++k) pp.p[k] = d_in[k < 2 ? k : k + 1];   // skip mask

    char* ws = (char*)d_ws;
    u16* arena = (u16*)ws;
    #define AP(k) ((const u16*)ws + h_seg_off[k])
    int*   mmode = (int*)(ws + 1835008);
    float* tokf  = (float*)(ws + 2097152);      // 16 MB
    u16*   tokb  = (u16*)(ws + 18874368);       //  8 MB
    const size_t base = 27262976;
    const size_t MB = 1048576ULL;

    // adaptive splits vs ws_size: attn needs base + 7*NB MB
    int NB = 8;
    while (NB > 1 && base + (size_t)NB * 7 * MB > ws_size) NB >>= 1;

    u16*   qb  = (u16*)(ws + base);                       // NB MB
    u16*   kb  = (u16*)(ws + base + (size_t)NB * MB);     // NB MB
    u16*   v2b = (u16*)(ws + base + (size_t)NB * 2 * MB); // NB MB
    float* v1f = (float*)(ws + base + (size_t)NB * 3 * MB); // 2*NB MB
    u16*   sb  = (u16*)(ws + base + (size_t)NB * 5 * MB);   // 2*NB MB
    u16*   ob  = qb;                              // q dead after attn_s

    convert_params<<<1024, 256, 0, stream>>>(pp, arena, mask, mmode);
    assemble_kernel<<<4096, 256, 0, stream>>>(AP(0), AP(1), mask, mmode,
                                              AP(2), AP(3), AP(4), AP(5), AP(6), tokf, tokb);

    for (int l = 0; l < 3; ++l) {
        const u16* Wq_l  = AP(7)  + l * 16384;
        const u16* Wk_l  = AP(8)  + l * 16384;
        const u16* Wv1_l = AP(9)  + l * 16384;
        const u16* Wv2_l = AP(10) + l * 16384;
        const u16* Wo_l  = AP(11) + l * 16384;
        const u16* bo_l  = AP(12) + l * 128;
        const u16* g1_l  = AP(13) + l * 128;
        const u16* be1_l = AP(14) + l * 128;
        const u16* W1_l  = AP(15) + l * 65536;
        const u16* b1_l  = AP(16) + l * 512;
        const u16* W2_l  = AP(17) + l * 65536;
        const u16* b2_l  = AP(18) + l * 128;
        const u16* g2_l  = AP(19) + l * 128;
        const u16* be2_l = AP(20) + l * 128;

        for (int r = 0; r < 8 / NB; ++r) {
            size_t rowOff = (size_t)r * NB * 4096;
            gemm_kernel<<<dim3(NB * 32, 4), 512, 0, stream>>>(
                tokb + rowOff * 128, 128, Wq_l, Wk_l, Wv1_l, Wv2_l,
                128, (const u16*)0, 128, 3, (u16*)0, 0, v1f, qb, kb, v2b,
                (const u16*)0, (const u16*)0, (u16*)0);
            attn_s_kernel<<<NB * 256, 64, 0, stream>>>(qb, kb, sb);
            attn_o_kernel<<<dim3(NB * 4, 8, 2), 256, 0, stream>>>(sb, v1f, v2b, ob);
            gemm_kernel<<<dim3(NB * 32, 1), 512, 0, stream>>>(
                ob, 128, Wo_l, (const u16*)0, (const u16*)0, (const u16*)0,
                128, bo_l, 128, 4, (u16*)0, 0, tokf + rowOff * 128,
                (u16*)0, (u16*)0, (u16*)0,
                g1_l, be1_l, tokb + rowOff * 128);
        }
        ff_kernel<<<256, 512, 0, stream>>>(tokb, W1_l, b1_l, W2_l, b2_l,
                                           g2_l, be2_l, tokf, tokb);
    }
    out_kernel<<<2, 256, 0, stream>>>(tokf, AP(21), AP(22), (float*)d_out);
}

// Round 13
// 392.264 us; speedup vs baseline: 1.2517x; 1.0275x over previous
//
#include <hip/hip_runtime.h>

typedef unsigned short u16;
typedef __attribute__((ext_vector_type(8))) short bf16x8;
typedef __attribute__((ext_vector_type(4))) float f32x4;

#define INV_SCALE 0.17677669529663687f

static __device__ __forceinline__ float b2f(u16 u) {
    union { unsigned int i; float f; } v; v.i = ((unsigned int)u) << 16; return v.f;
}
static __device__ __forceinline__ u16 f2b(float f) {
    union { float f; unsigned int i; } v; v.f = f;
    unsigned int r = (v.i + 0x7FFFu + ((v.i >> 16) & 1u)) >> 16;
    return (u16)r;
}

// ---- param arena segment table (bf16 elements), shared host/device ----
// Weight segs 7-11 (128x128/layer), 15 (W1), 17 (W2) are stored TRANSPOSED [n][k].
#define NSEG 23
__device__ __constant__ int d_seg_off[NSEG + 1] = {
    0, 8192, 270336, 272384, 272512, 273536, 273664, 273792, 322944, 372096,
    421248, 470400, 519552, 519936, 520320, 520704, 717312, 718848, 915456,
    915840, 916224, 916608, 916736, 916744};
static const int h_seg_off[NSEG + 1] = {
    0, 8192, 270336, 272384, 272512, 273536, 273664, 273792, 322944, 372096,
    421248, 470400, 519552, 519936, 520320, 520704, 717312, 718848, 915456,
    915840, 916224, 916608, 916736, 916744};
#define ARENA_TOTAL 916744

struct ParamPtrs { const void* p[NSEG]; };

// ---------------------------------------------------------------- param convert + mask probe
__global__ __launch_bounds__(256) void convert_params(ParamPtrs pp, u16* __restrict__ arena,
                                                      const void* __restrict__ mask,
                                                      int* __restrict__ mode) {
    if (blockIdx.x == 0) {
        __shared__ int f16, f32s, u8s;
        int tid = threadIdx.x;
        if (tid == 0) { f16 = 0; f32s = 0; u8s = 0; }
        __syncthreads();
        const u16* mu = (const u16*)mask;
        const unsigned int* mw = (const unsigned int*)mask;
        if (mu[2 * tid] == 0x3F80u) atomicOr(&f16, 1);
        if (mw[tid] == 0x3F800000u) atomicOr(&f32s, 1);
        if (mw[tid] > 1u) atomicOr(&u8s, 1);
        __syncthreads();
        if (tid == 0) mode[0] = f16 ? 0 : (f32s ? 3 : (u8s ? 1 : 2));
    }
    const unsigned int probe = ((const unsigned int*)pp.p[13])[0];   // ln1_g[0] == 1.0
    const bool f32 = (probe == 0x3F800000u);
    for (int e = blockIdx.x * 256 + threadIdx.x; e < ARENA_TOTAL; e += gridDim.x * 256) {
        int k = 0;
        #pragma unroll
        for (int s2 = 1; s2 < NSEG; ++s2) if (e >= d_seg_off[s2]) k = s2;
        int local = e - d_seg_off[k];
        // transposed weight segments: arena [l][n][k] <- src [l][k][n]
        int src = local;
        if (k >= 7 && k <= 11) {                 // [L][128k][128n] -> [L][128n][128k]
            int l = local >> 14, rem = local & 16383;
            int n = rem >> 7, kk = rem & 127;
            src = (l << 14) + kk * 128 + n;
        } else if (k == 15) {                    // W1 [L][128k][512n] -> [L][512n][128k]
            int l = local >> 16, rem = local & 65535;
            int n = rem >> 7, kk = rem & 127;
            src = (l << 16) + kk * 512 + n;
        } else if (k == 17) {                    // W2 [L][512k][128n] -> [L][128n][512k]
            int l = local >> 16, rem = local & 65535;
            int n = rem >> 9, kk = rem & 511;
            src = (l << 16) + kk * 128 + n;
        }
        u16 v;
        if (k == 22 && local >= 1) v = 0;   // bout padded 1 -> 8
        else v = f32 ? f2b(((const float*)pp.p[k])[src]) : ((const u16*)pp.p[k])[src];
        arena[e] = v;
    }
}

// ---------------------------------------------------------------- tok assembly (mask fused)
__global__ __launch_bounds__(256) void assemble_kernel(
    const u16* __restrict__ x, const u16* __restrict__ ea,
    const void* __restrict__ mask, const int* __restrict__ modeptr,
    const u16* __restrict__ nodeW, const u16* __restrict__ nodeB,
    const u16* __restrict__ edgeW, const u16* __restrict__ edgeB, const u16* __restrict__ noedge,
    float* __restrict__ tokf, u16* __restrict__ tokb)
{
    const int md = modeptr[0];
    int g = blockIdx.x * 256 + threadIdx.x;      // [0, 1048576)
    int t = g >> 5, dq = g & 31, d0 = dq * 4;
    int b = t >> 12, i = (t >> 6) & 63, j = t & 63;
    float v[4];
    if (i == j) {
        #pragma unroll
        for (int c = 0; c < 4; c++) v[c] = b2f(nodeB[d0 + c]);
        #pragma unroll
        for (int e = 0; e < 16; e++) {
            float xe = b2f(x[(b * 64 + i) * 16 + e]);
            #pragma unroll
            for (int c = 0; c < 4; c++) v[c] += xe * b2f(nodeW[e * 128 + d0 + c]);
        }
    } else {
        bool edge;
        if (md == 0)      edge = ((const u16*)mask)[t] != 0;
        else if (md == 3) edge = ((const float*)mask)[t] != 0.0f;
        else if (md == 1) edge = ((const unsigned char*)mask)[t] != 0;
        else              edge = ((const unsigned int*)mask)[t] != 0;
        if (edge) {
            #pragma unroll
            for (int c = 0; c < 4; c++) v[c] = b2f(edgeB[d0 + c]);
            #pragma unroll
            for (int e = 0; e < 8; e++) {
                float ae = b2f(ea[t * 8 + e]);
                #pragma unroll
                for (int c = 0; c < 4; c++) v[c] += ae * b2f(edgeW[e * 128 + d0 + c]);
            }
        } else {
            #pragma unroll
            for (int c = 0; c < 4; c++) v[c] = b2f(noedge[d0 + c]);
        }
    }
    *(float4*)(tokf + (size_t)t * 128 + d0) = make_float4(v[0], v[1], v[2], v[3]);
    u16 pk[4];
    #pragma unroll
    for (int c = 0; c < 4; c++) pk[c] = f2b(v[c]);
    *(uint2*)(tokb + (size_t)t * 128 + d0) = *(uint2*)pk;
}

// ---------------------------------------------------------------- qkv GEMM (512 thr, 8 waves, BM=128)
// B TRANSPOSED [128 n][128 k]; vector uint4 staging. by: 0=q 1=k 2=v1(fp32) 3=v2.
__global__ __launch_bounds__(512) void gemm_qkv_kernel(
    const u16* __restrict__ A,
    const u16* __restrict__ B0, const u16* __restrict__ B1,
    const u16* __restrict__ B2, const u16* __restrict__ B3,
    float* __restrict__ v1f,
    u16* __restrict__ qb, u16* __restrict__ kb, u16* __restrict__ v2b)
{
    __shared__ __align__(16) u16 smem[2 * 128 * 72];   // 36864 B
    u16* As = smem;
    u16* Bs = smem + 128 * 72;
    int tid = threadIdx.x;
    int m0 = blockIdx.x * 128;
    int by = blockIdx.y;
    const u16* Bp = (by == 0) ? B0 : (by == 1) ? B1 : (by == 2) ? B2 : B3;

    int w = tid >> 6, lane = tid & 63;
    int q = lane >> 4, r16 = lane & 15;
    int rw = (w >> 1) * 32, cw = (w & 1) * 64;

    f32x4 acc[2][4];
    #pragma unroll
    for (int mi = 0; mi < 2; mi++)
        #pragma unroll
        for (int ni = 0; ni < 4; ni++) acc[mi][ni] = (f32x4){0.f, 0.f, 0.f, 0.f};

    #pragma unroll
    for (int kt = 0; kt < 2; ++kt) {
        int k0 = kt * 64;
        __syncthreads();
        #pragma unroll
        for (int it = 0; it < 2; ++it) {               // A: 128 x 64 (1024 uint4)
            int idx = tid + it * 512;
            int row = idx >> 3, ch = idx & 7;
            uint4 d = *(const uint4*)(A + (size_t)(m0 + row) * 128 + k0 + ch * 8);
            *(uint4*)&As[row * 72 + ch * 8] = d;
        }
        #pragma unroll
        for (int it = 0; it < 2; ++it) {               // B^T: 128 n x 64 k (1024 uint4, vector)
            int idx = tid + it * 512;
            int n = idx >> 3, ch = idx & 7;
            uint4 d = *(const uint4*)(Bp + (size_t)n * 128 + k0 + ch * 8);
            int ch2 = ch ^ ((n >> 3) & 7);
            *(uint4*)&Bs[n * 72 + ch2 * 8] = d;
        }
        __syncthreads();
        #pragma unroll
        for (int ks = 0; ks < 2; ++ks) {
            bf16x8 fa[2], fb[4];
            #pragma unroll
            for (int mi = 0; mi < 2; mi++)
                fa[mi] = *(const bf16x8*)&As[(rw + mi * 16 + r16) * 72 + ks * 32 + q * 8];
            #pragma unroll
            for (int ni = 0; ni < 4; ni++) {
                int n = cw + ni * 16 + r16;
                int ch2 = (ks * 4 + q) ^ ((n >> 3) & 7);
                fb[ni] = *(const bf16x8*)&Bs[n * 72 + ch2 * 8];
            }
            #pragma unroll
            for (int mi = 0; mi < 2; mi++)
                #pragma unroll
                for (int ni = 0; ni < 4; ni++)
                    acc[mi][ni] = __builtin_amdgcn_mfma_f32_16x16x32_bf16(fa[mi], fb[ni], acc[mi][ni], 0, 0, 0);
        }
    }

    // ---------------- epilogue (scatter) ----------------
    int bl = m0 >> 12, it0 = (m0 >> 6) & 63;
    __syncthreads();
    if (by == 2) {
        // ---- v1f fp32 scatter: [bh][i][l][32] ----
        float* cf = (float*)smem;                      // [128][64] fp32, XOR-swizzled
        #pragma unroll
        for (int hp = 0; hp < 2; ++hp) {
            if (hp) __syncthreads();
            if ((cw >> 6) == hp) {
                #pragma unroll
                for (int mi = 0; mi < 2; mi++) {
                    #pragma unroll
                    for (int ni = 0; ni < 4; ni++) {
                        int colh = (cw & 63) + ni * 16 + r16;
                        int ch4 = colh >> 2, cl = colh & 3;
                        #pragma unroll
                        for (int rr = 0; rr < 4; rr++) {
                            int r = rw + mi * 16 + q * 4 + rr;
                            cf[r * 64 + (((ch4 ^ (r & 15)) << 2) | cl)] = acc[mi][ni][rr];
                        }
                    }
                }
            }
            __syncthreads();
            #pragma unroll
            for (int it = 0; it < 4; ++it) {
                int idx = tid + it * 512;          // (hh:1 | itl:1 | jt:6 | d4:3)
                int hh = idx >> 10, itl = (idx >> 9) & 1, jt = (idx >> 3) & 63, d4 = idx & 7;
                int r = itl * 64 + jt;
                int colh = hh * 32 + d4 * 4;
                f32x4 v = *(const f32x4*)&cf[r * 64 + (((colh >> 2) ^ (r & 15)) << 2)];
                int h = hp * 2 + hh;
                *(f32x4*)&v1f[((((size_t)(bl * 4 + h)) * 64 + it0 + itl) * 64 + jt) * 32 + d4 * 4] = v;
            }
        }
    } else {
        // ---- bf16 scatter paths: q/k/v2 ----
        u16* cs = smem;                                // [128][128] u16, XOR-swizzled
        #pragma unroll
        for (int mi = 0; mi < 2; mi++) {
            #pragma unroll
            for (int ni = 0; ni < 4; ni++) {
                int col = cw + ni * 16 + r16;
                int ch = col >> 3, cl = col & 7;
                #pragma unroll
                for (int rr = 0; rr < 4; rr++) {
                    int r = rw + mi * 16 + q * 4 + rr;
                    cs[r * 128 + (((ch ^ (r & 15)) << 3) | cl)] = f2b(acc[mi][ni][rr]);
                }
            }
        }
        __syncthreads();
        if (by == 0) {                                 // q: [bh][l=jt][i][32]
            #pragma unroll
            for (int it = 0; it < 4; ++it) {
                int idx = tid + it * 512;              // (h:2 | jt:6 | itl:1 | d8:2)
                int h = idx >> 9, jt = (idx >> 3) & 63, itl = (idx >> 2) & 1, d8 = idx & 3;
                int r = itl * 64 + jt, c8 = h * 4 + d8;
                uint4 d = *(const uint4*)&cs[r * 128 + ((c8 ^ (r & 15)) << 3)];
                *(uint4*)&qb[((((size_t)(bl * 4 + h)) * 64 + jt) * 64 + it0 + itl) * 32 + d8 * 8] = d;
            }
        } else {                                       // k / v2: [bh][i][j=jt][32]
            u16* dp = (by == 1) ? kb : v2b;
            #pragma unroll
            for (int it = 0; it < 4; ++it) {
                int idx = tid + it * 512;              // (h:2 | itl:1 | jt:6 | d8:2)
                int h = idx >> 9, itl = (idx >> 8) & 1, jt = (idx >> 2) & 63, d8 = idx & 3;
                int r = itl * 64 + jt, c8 = h * 4 + d8;
                uint4 d = *(const uint4*)&cs[r * 128 + ((c8 ^ (r & 15)) << 3)];
                *(uint4*)&dp[((((size_t)(bl * 4 + h)) * 64 + it0 + itl) * 64 + jt) * 32 + d8 * 8] = d;
            }
        }
    }
}

// ---------------------------------------------------------------- Wo GEMM + bias + residual + LN
// BM=64, 512 thr (8 waves: 4 rowgroups x 2 colgroups), grid 512 -> 2 blocks/CU.
__global__ __launch_bounds__(512) void gemm_ln64_kernel(
    const u16* __restrict__ A,                     // ob [32768][128]
    const u16* __restrict__ BT,                    // WoT [128 n][128 k]
    const u16* __restrict__ bias,
    float* __restrict__ tokf,
    const u16* __restrict__ lng, const u16* __restrict__ lnb, u16* __restrict__ tokbO)
{
    __shared__ __align__(16) u16 smem[64 * 72 + 128 * 72];   // 27648 B
    u16* As = smem;
    u16* Bs = smem + 64 * 72;
    int tid = threadIdx.x;
    int m0 = blockIdx.x * 64;
    int w = tid >> 6, lane = tid & 63;
    int q = lane >> 4, r16 = lane & 15;
    int rw = (w >> 1) * 16, cw = (w & 1) * 64;

    f32x4 acc[4];
    #pragma unroll
    for (int ni = 0; ni < 4; ni++) acc[ni] = (f32x4){0.f, 0.f, 0.f, 0.f};

    #pragma unroll
    for (int kt = 0; kt < 2; ++kt) {
        int k0 = kt * 64;
        __syncthreads();
        {                                              // A: 64 x 64 (512 uint4, 1/thread)
            int row = tid >> 3, ch = tid & 7;
            uint4 d = *(const uint4*)(A + (size_t)(m0 + row) * 128 + k0 + ch * 8);
            *(uint4*)&As[row * 72 + ch * 8] = d;
        }
        #pragma unroll
        for (int it = 0; it < 2; ++it) {               // B^T: 128 n x 64 k (1024 uint4)
            int idx = tid + it * 512;
            int n = idx >> 3, ch = idx & 7;
            uint4 d = *(const uint4*)(BT + (size_t)n * 128 + k0 + ch * 8);
            int ch2 = ch ^ ((n >> 3) & 7);
            *(uint4*)&Bs[n * 72 + ch2 * 8] = d;
        }
        __syncthreads();
        #pragma unroll
        for (int ks = 0; ks < 2; ++ks) {
            bf16x8 fa = *(const bf16x8*)&As[(rw + r16) * 72 + ks * 32 + q * 8];
            #pragma unroll
            for (int ni = 0; ni < 4; ni++) {
                int n = cw + ni * 16 + r16;
                int ch2 = (ks * 4 + q) ^ ((n >> 3) & 7);
                bf16x8 fb = *(const bf16x8*)&Bs[n * 72 + ch2 * 8];
                acc[ni] = __builtin_amdgcn_mfma_f32_16x16x32_bf16(fa, fb, acc[ni], 0, 0, 0);
            }
        }
    }

    // ---- epilogue: bias + residual + LayerNorm -> tokf + tokbO ----
    __syncthreads();
    float* cf  = (float*)smem;                         // [64][64] fp32 (16 KB)
    float* rsm = cf + 64 * 64;                         // [2][64]
    float* rqm = rsm + 128;
    int half = cw >> 6;
    #pragma unroll
    for (int ni = 0; ni < 4; ni++) {
        int col = cw + ni * 16 + r16;
        float bb = b2f(bias[col]);
        #pragma unroll
        for (int rr = 0; rr < 4; rr++) {
            int r = rw + q * 4 + rr;
            acc[ni][rr] += bb + tokf[(size_t)(m0 + r) * 128 + col];
        }
    }
    #pragma unroll
    for (int rr = 0; rr < 4; rr++) {
        float s = 0.f, sq = 0.f;
        #pragma unroll
        for (int ni = 0; ni < 4; ni++) { float t = acc[ni][rr]; s += t; sq += t * t; }
        #pragma unroll
        for (int off = 1; off < 16; off <<= 1) {
            s  += __shfl_xor(s,  off, 16);
            sq += __shfl_xor(sq, off, 16);
        }
        if (r16 == 0) {
            int r = rw + q * 4 + rr;
            rsm[half * 64 + r] = s;
            rqm[half * 64 + r] = sq;
        }
    }
    __syncthreads();
    float gl[4], bv[4];
    #pragma unroll
    for (int ni = 0; ni < 4; ni++) {
        int col = cw + ni * 16 + r16;
        gl[ni] = b2f(lng[col]);
        bv[ni] = b2f(lnb[col]);
    }
    #pragma unroll
    for (int rr = 0; rr < 4; rr++) {
        int r = rw + q * 4 + rr;
        float tot = rsm[r] + rsm[64 + r];
        float tq  = rqm[r] + rqm[64 + r];
        float mean = tot * 0.0078125f;
        float var  = tq * 0.0078125f - mean * mean;
        float rstd = rsqrtf(var + 1e-5f);
        #pragma unroll
        for (int ni = 0; ni < 4; ni++)
            acc[ni][rr] = (acc[ni][rr] - mean) * rstd * gl[ni] + bv[ni];
    }
    #pragma unroll
    for (int hp = 0; hp < 2; ++hp) {
        __syncthreads();
        if (half == hp) {
            #pragma unroll
            for (int ni = 0; ni < 4; ni++) {
                int colh = (cw & 63) + ni * 16 + r16;
                int ch4 = colh >> 2, cl = colh & 3;
                #pragma unroll
                for (int rr = 0; rr < 4; rr++) {
                    int r = rw + q * 4 + rr;
                    cf[r * 64 + (((ch4 ^ (r & 15)) << 2) | cl)] = acc[ni][rr];
                }
            }
        }
        __syncthreads();
        #pragma unroll
        for (int it = 0; it < 2; ++it) {
            int idx = tid + it * 512;              // (r:6 | c4:4)
            int r = idx >> 4, c4 = idx & 15;
            f32x4 v = *(const f32x4*)&cf[r * 64 + ((c4 ^ (r & 15)) << 2)];
            int col = hp * 64 + c4 * 4;
            *(f32x4*)(tokf + (size_t)(m0 + r) * 128 + col) = v;
            u16 pk[4];
            #pragma unroll
            for (int e = 0; e < 4; e++) pk[e] = f2b(v[e]);
            *(uint2*)(tokbO + (size_t)(m0 + r) * 128 + col) = *(uint2*)pk;
        }
    }
}

// ---------------------------------------------------------------- fused FF (BM=64, 512 thr, 8 waves)
// W1T [512 n][128 k], W2T [128 n][512 k]; grid 512 -> 2 blocks/CU.
__global__ __launch_bounds__(512) void ff_kernel(
    const u16* __restrict__ A,                     // tokb (bf16, post-LN1)
    const u16* __restrict__ W1T, const u16* __restrict__ b1,
    const u16* __restrict__ W2T, const u16* __restrict__ b2,
    const u16* __restrict__ lng, const u16* __restrict__ lnb,
    float* __restrict__ tokf, u16* __restrict__ tokbO)
{
    __shared__ __align__(16) u16 smem[64 * 72 + 128 * 72];   // 27648 B
    u16* As = smem;
    u16* Bs = smem + 64 * 72;
    int tid = threadIdx.x;
    int m0 = blockIdx.x * 64;
    int w = tid >> 6, lane = tid & 63;
    int q = lane >> 4, r16 = lane & 15;
    int rw = (w >> 1) * 16, cw = (w & 1) * 64;

    f32x4 acc2[4];
    #pragma unroll
    for (int ni = 0; ni < 4; ni++) acc2[ni] = (f32x4){0.f, 0.f, 0.f, 0.f};

    for (int hs = 0; hs < 4; ++hs) {
        f32x4 acc1[4];
        #pragma unroll
        for (int ni = 0; ni < 4; ni++) acc1[ni] = (f32x4){0.f, 0.f, 0.f, 0.f};
        #pragma unroll
        for (int kt = 0; kt < 2; ++kt) {
            int k0 = kt * 64;
            __syncthreads();
            {                                          // A: 64 x 64 (tokb)
                int row = tid >> 3, ch = tid & 7;
                uint4 d = *(const uint4*)(A + (size_t)(m0 + row) * 128 + k0 + ch * 8);
                *(uint4*)&As[row * 72 + ch * 8] = d;
            }
            #pragma unroll
            for (int it = 0; it < 2; ++it) {           // B: W1T rows hs*128..
                int idx = tid + it * 512;
                int n = idx >> 3, ch = idx & 7;
                uint4 d = *(const uint4*)(W1T + (size_t)(hs * 128 + n) * 128 + k0 + ch * 8);
                int ch2 = ch ^ ((n >> 3) & 7);
                *(uint4*)&Bs[n * 72 + ch2 * 8] = d;
            }
            __syncthreads();
            #pragma unroll
            for (int ks = 0; ks < 2; ++ks) {
                bf16x8 fa = *(const bf16x8*)&As[(rw + r16) * 72 + ks * 32 + q * 8];
                #pragma unroll
                for (int ni = 0; ni < 4; ni++) {
                    int n = cw + ni * 16 + r16;
                    int ch2 = (ks * 4 + q) ^ ((n >> 3) & 7);
                    bf16x8 fb = *(const bf16x8*)&Bs[n * 72 + ch2 * 8];
                    acc1[ni] = __builtin_amdgcn_mfma_f32_16x16x32_bf16(fa, fb, acc1[ni], 0, 0, 0);
                }
            }
        }
        #pragma unroll
        for (int half = 0; half < 2; ++half) {
            __syncthreads();
            if ((w & 1) == half) {                     // 4 waves own these 64 hidden cols
                #pragma unroll
                for (int ni = 0; ni < 4; ni++) {
                    int kl = ni * 16 + r16;
                    float bb = b2f(b1[hs * 128 + half * 64 + kl]);
                    #pragma unroll
                    for (int rr = 0; rr < 4; rr++) {
                        int row = rw + q * 4 + rr;
                        As[row * 72 + kl] = f2b(fmaxf(acc1[ni][rr] + bb, 0.f));
                    }
                }
            }
            #pragma unroll
            for (int it = 0; it < 2; ++it) {           // B: W2T [n][512], k-slice hs*128+half*64
                int idx = tid + it * 512;
                int n = idx >> 3, ch = idx & 7;
                uint4 d = *(const uint4*)(W2T + (size_t)n * 512 + hs * 128 + half * 64 + ch * 8);
                int ch2 = ch ^ ((n >> 3) & 7);
                *(uint4*)&Bs[n * 72 + ch2 * 8] = d;
            }
            __syncthreads();
            #pragma unroll
            for (int ks = 0; ks < 2; ++ks) {
                bf16x8 fa = *(const bf16x8*)&As[(rw + r16) * 72 + ks * 32 + q * 8];
                #pragma unroll
                for (int ni = 0; ni < 4; ni++) {
                    int n = cw + ni * 16 + r16;
                    int ch2 = (ks * 4 + q) ^ ((n >> 3) & 7);
                    bf16x8 fb = *(const bf16x8*)&Bs[n * 72 + ch2 * 8];
                    acc2[ni] = __builtin_amdgcn_mfma_f32_16x16x32_bf16(fa, fb, acc2[ni], 0, 0, 0);
                }
            }
        }
    }

    // ---- epilogue: bias b2 + residual tokf + LayerNorm -> tokf + tokbO ----
    __syncthreads();
    float* cf  = (float*)smem;
    float* rsm = cf + 64 * 64;
    float* rqm = rsm + 128;
    int half = cw >> 6;
    #pragma unroll
    for (int ni = 0; ni < 4; ni++) {
        int col = cw + ni * 16 + r16;
        float bb = b2f(b2[col]);
        #pragma unroll
        for (int rr = 0; rr < 4; rr++) {
            int r = rw + q * 4 + rr;
            acc2[ni][rr] += bb + tokf[(size_t)(m0 + r) * 128 + col];
        }
    }
    #pragma unroll
    for (int rr = 0; rr < 4; rr++) {
        float s = 0.f, sq = 0.f;
        #pragma unroll
        for (int ni = 0; ni < 4; ni++) { float t = acc2[ni][rr]; s += t; sq += t * t; }
        #pragma unroll
        for (int off = 1; off < 16; off <<= 1) {
            s  += __shfl_xor(s,  off, 16);
            sq += __shfl_xor(sq, off, 16);
        }
        if (r16 == 0) {
            int r = rw + q * 4 + rr;
            rsm[half * 64 + r] = s;
            rqm[half * 64 + r] = sq;
        }
    }
    __syncthreads();
    float gl[4], bv[4];
    #pragma unroll
    for (int ni = 0; ni < 4; ni++) {
        int col = cw + ni * 16 + r16;
        gl[ni] = b2f(lng[col]);
        bv[ni] = b2f(lnb[col]);
    }
    #pragma unroll
    for (int rr = 0; rr < 4; rr++) {
        int r = rw + q * 4 + rr;
        float tot = rsm[r] + rsm[64 + r];
        float tq  = rqm[r] + rqm[64 + r];
        float mean = tot * 0.0078125f;
        float var  = tq * 0.0078125f - mean * mean;
        float rstd = rsqrtf(var + 1e-5f);
        #pragma unroll
        for (int ni = 0; ni < 4; ni++)
            acc2[ni][rr] = (acc2[ni][rr] - mean) * rstd * gl[ni] + bv[ni];
    }
    #pragma unroll
    for (int hp = 0; hp < 2; ++hp) {
        __syncthreads();
        if (half == hp) {
            #pragma unroll
            for (int ni = 0; ni < 4; ni++) {
                int colh = (cw & 63) + ni * 16 + r16;
                int ch4 = colh >> 2, cl = colh & 3;
                #pragma unroll
                for (int rr = 0; rr < 4; rr++) {
                    int r = rw + q * 4 + rr;
                    cf[r * 64 + (((ch4 ^ (r & 15)) << 2) | cl)] = acc2[ni][rr];
                }
            }
        }
        __syncthreads();
        #pragma unroll
        for (int it = 0; it < 2; ++it) {
            int idx = tid + it * 512;              // (r:6 | c4:4)
            int r = idx >> 4, c4 = idx & 15;
            f32x4 v = *(const f32x4*)&cf[r * 64 + ((c4 ^ (r & 15)) << 2)];
            int col = hp * 64 + c4 * 4;
            *(f32x4*)(tokf + (size_t)(m0 + r) * 128 + col) = v;
            u16 pk[4];
            #pragma unroll
            for (int e = 0; e < 4; e++) pk[e] = f2b(v[e]);
            *(uint2*)(tokbO + (size_t)(m0 + r) * 128 + col) = *(uint2*)pk;
        }
    }
}

// ---------------------------------------------------------------- s = QK^T/scale (bf16 out, raw logits)
__global__ __launch_bounds__(64) void attn_s_kernel(
    const u16* __restrict__ qb, const u16* __restrict__ kb, u16* __restrict__ s)
{
    __shared__ __align__(16) u16 sm[64 * 80];          // qs(64x40) + ks(64x40); reused as cs(64x72)
    u16* qs  = sm;
    u16* ks_ = sm + 64 * 40;
    int g = blockIdx.x;
    int l = g & 63, bh = g >> 6;
    const u16* Q = qb + ((size_t)bh * 64 + l) * 2048;
    const u16* Kp = kb + ((size_t)bh * 64 + l) * 2048;
    int lane = threadIdx.x;
    #pragma unroll
    for (int it = 0; it < 4; ++it) {
        int idx = lane + it * 64;
        int row = idx >> 2, c4 = idx & 3;
        *(uint4*)&qs[row * 40 + c4 * 8] = *(const uint4*)(Q + row * 32 + c4 * 8);
        *(uint4*)&ks_[row * 40 + c4 * 8] = *(const uint4*)(Kp + row * 32 + c4 * 8);
    }
    __syncthreads();
    int q = lane >> 4, r16 = lane & 15;
    f32x4 acc[4][4];
    #pragma unroll
    for (int mi = 0; mi < 4; mi++)
        #pragma unroll
        for (int ni = 0; ni < 4; ni++) acc[mi][ni] = (f32x4){0.f, 0.f, 0.f, 0.f};
    bf16x8 fa[4], fb[4];
    #pragma unroll
    for (int mi = 0; mi < 4; mi++) fa[mi] = *(const bf16x8*)&qs[(mi * 16 + r16) * 40 + q * 8];
    #pragma unroll
    for (int ni = 0; ni < 4; ni++) fb[ni] = *(const bf16x8*)&ks_[(ni * 16 + r16) * 40 + q * 8];
    #pragma unroll
    for (int mi = 0; mi < 4; mi++)
        #pragma unroll
        for (int ni = 0; ni < 4; ni++)
            acc[mi][ni] = __builtin_amdgcn_mfma_f32_16x16x32_bf16(fa[mi], fb[ni], acc[mi][ni], 0, 0, 0);
    // stage C tile in LDS, then coalesced stores
    __syncthreads();
    u16* cs = sm;                                      // 64 x 72
    #pragma unroll
    for (int mi = 0; mi < 4; mi++)
        #pragma unroll
        for (int ni = 0; ni < 4; ni++)
            #pragma unroll
            for (int rr = 0; rr < 4; rr++)
                cs[(mi * 16 + q * 4 + rr) * 72 + ni * 16 + r16] = f2b(acc[mi][ni][rr] * INV_SCALE);
    __syncthreads();
    u16* sb = s + (size_t)bh * 262144 + l * 64;
    #pragma unroll
    for (int it = 0; it < 8; ++it) {
        int row = it * 8 + (lane >> 3);
        uint4 d = *(const uint4*)&cs[row * 72 + (lane & 7) * 8];
        *(uint4*)&sb[(size_t)row * 4096 + (lane & 7) * 8] = d;
    }
}

// ---------------------------------------------------------------- o = softmax_l(s) * v1 * v2  (softmax fused)
// block = (bh, 8-i-group, j-half), 256 threads (4 waves), grid NB*4 x 8 x 2 = 512 -> 2 blocks/CU.
__global__ __launch_bounds__(256) void attn_o_kernel(
    const u16* __restrict__ a, const float* __restrict__ v1f, const u16* __restrict__ v2b,
    u16* __restrict__ ob)
{
    __shared__ __align__(16) float v2s[4 * 1152];   // 18432 B, [l][32 j][36] f32
    __shared__ __align__(16) u16   as_[8 * 4 * 32]; // 2048 B,  [i][l][32 j]
    __shared__ __align__(16) float v1s[8 * 4 * 32]; // 4096 B,  [i][l][32 d]
    int bh = blockIdx.x;
    int i0 = blockIdx.y * 8;
    int jh = blockIdx.z;                               // j-half
    int bl = bh >> 2, h = bh & 3;
    int tid = threadIdx.x;
    int j32 = tid & 31;
    int ih = (tid >> 5) & 1;                           // i-half within block
    int dh = (tid >> 6) * 8;                           // d-chunk base (wave id)
    int jg = jh * 32 + j32;                            // global j
    const u16*   v2base = v2b + (size_t)bh * 131072;
    const float* v1base = v1f + (size_t)bh * 131072 + (size_t)i0 * 2048;
    const u16*   abase  = a + (size_t)bh * 262144 + (size_t)i0 * 4096;

    // load-index precompute
    int lz[2], jz[2], cz[2];
    #pragma unroll
    for (int it = 0; it < 2; ++it) {
        int idx = tid + it * 256;            // [0,512) uint4s for v2 (4l x 32j x 4)
        lz[it] = idx >> 7; jz[it] = (idx >> 2) & 31; cz[it] = idx & 3;
    }
    int ia = tid >> 5, la = (tid >> 3) & 3, jaq = tid & 7;         // a: uint2/thread
    int iv = tid >> 5, lv = (tid >> 3) & 3, dvq = (tid & 7) * 4;   // v1: f32x4/thread

    uint4 pv2[2]; uint2 pa; f32x4 pv1;

#define LOAD_CHUNK(l0_)                                                             \
    _Pragma("unroll")                                                               \
    for (int it = 0; it < 2; ++it)                                                  \
        pv2[it] = *(const uint4*)(v2base + ((size_t)((l0_) + lz[it]) * 64 + jh * 32 + jz[it]) * 32 + cz[it] * 8); \
    pa  = *(const uint2*)(abase + (size_t)ia * 4096 + ((l0_) + la) * 64 + jh * 32 + jaq * 4); \
    pv1 = *(const f32x4*)(v1base + (size_t)iv * 2048 + ((l0_) + lv) * 32 + dvq);

#define STORE_CHUNK()                                                               \
    _Pragma("unroll")                                                               \
    for (int it = 0; it < 2; ++it) {                                                \
        const u16* ds = (const u16*)&pv2[it];                                       \
        float* dst = &v2s[lz[it] * 1152 + jz[it] * 36 + cz[it] * 8];                \
        _Pragma("unroll")                                                           \
        for (int e = 0; e < 8; e++) dst[e] = b2f(ds[e]);                            \
    }                                                                               \
    *(uint2*)&as_[ia * 128 + la * 32 + jaq * 4] = pa;                               \
    *(f32x4*)&v1s[iv * 128 + lv * 32 + dvq] = pv1;

    float acc[4][8];
    float Z[4];
    #pragma unroll
    for (int i = 0; i < 4; i++) {
        Z[i] = 0.f;
        #pragma unroll
        for (int e = 0; e < 8; e++) acc[i][e] = 0.f;
    }

    LOAD_CHUNK(0);
    for (int ch = 0; ch < 16; ++ch) {
        if (ch) __syncthreads();             // previous chunk's readers done
        STORE_CHUNK();
        if (ch + 1 < 16) LOAD_CHUNK((ch + 1) * 4);
        __syncthreads();
        #pragma unroll
        for (int lc = 0; lc < 4; ++lc) {
            const float* vp = &v2s[lc * 1152 + j32 * 36 + dh];
            float v2r[8];
            *(f32x4*)&v2r[0] = *(const f32x4*)vp;
            *(f32x4*)&v2r[4] = *(const f32x4*)(vp + 4);
            #pragma unroll
            for (int ii = 0; ii < 4; ++ii) {
                int iL = ih * 4 + ii;
                float sv = b2f(as_[iL * 128 + lc * 32 + j32]);
                float av = __expf(sv);
                Z[ii] += av;
                const float* v1p = &v1s[iL * 128 + lc * 32 + dh];   // broadcast reads
                #pragma unroll
                for (int e = 0; e < 8; e++)
                    acc[ii][e] += (av * v1p[e]) * v2r[e];
            }
        }
    }
#undef LOAD_CHUNK
#undef STORE_CHUNK

    #pragma unroll
    for (int ii = 0; ii < 4; ++ii) {
        int iL = ih * 4 + ii;
        float sc = 1.0f / Z[ii];
        u16 tmp[8];
        #pragma unroll
        for (int e = 0; e < 8; e++) tmp[e] = f2b(acc[ii][e] * sc);
        *(uint4*)(ob + ((size_t)(bl * 64 + i0 + iL) * 64 + jg) * 128 + h * 32 + dh) = *(uint4*)tmp;
    }
}

// ---------------------------------------------------------------- final diag head (fp32 out)
__global__ __launch_bounds__(256) void out_kernel(
    const float* __restrict__ tokf, const u16* __restrict__ Wout, const u16* __restrict__ bout,
    float* __restrict__ out)
{
    int g = blockIdx.x * 256 + threadIdx.x;   // [0,512)
    int b = g >> 6, i = g & 63;
    const float* p = tokf + ((size_t)(b * 64 + i) * 64 + i) * 128;
    float s = b2f(bout[0]);
    #pragma unroll
    for (int d = 0; d < 128; d++) s += p[d] * b2f(Wout[d]);
    out[g] = s;
}

// ---------------------------------------------------------------- launch
extern "C" void kernel_launch(void* const* d_in, const int* in_sizes, int n_in,
                              void* d_out, int out_size, void* d_ws, size_t ws_size,
                              hipStream_t stream) {
    const void* mask = d_in[2];
    ParamPtrs pp;
    for (int k = 0; k < NSEG; ++k) pp.p[k] = d_in[k < 2 ? k : k + 1];   // skip mask

    char* ws = (char*)d_ws;
    u16* arena = (u16*)ws;
    #define AP(k) ((const u16*)ws + h_seg_off[k])
    int*   mmode = (int*)(ws + 1835008);
    float* tokf  = (float*)(ws + 2097152);      // 16 MB
    u16*   tokb  = (u16*)(ws + 18874368);       //  8 MB
    const size_t base = 27262976;
    const size_t MB = 1048576ULL;

    // adaptive splits vs ws_size: attn needs base + 7*NB MB
    int NB = 8;
    while (NB > 1 && base + (size_t)NB * 7 * MB > ws_size) NB >>= 1;

    u16*   qb  = (u16*)(ws + base);                       // NB MB
    u16*   kb  = (u16*)(ws + base + (size_t)NB * MB);     // NB MB
    u16*   v2b = (u16*)(ws + base + (size_t)NB * 2 * MB); // NB MB
    float* v1f = (float*)(ws + base + (size_t)NB * 3 * MB); // 2*NB MB
    u16*   sb  = (u16*)(ws + base + (size_t)NB * 5 * MB);   // 2*NB MB
    u16*   ob  = qb;                              // q dead after attn_s

    convert_params<<<1024, 256, 0, stream>>>(pp, arena, mask, mmode);
    assemble_kernel<<<4096, 256, 0, stream>>>(AP(0), AP(1), mask, mmode,
                                              AP(2), AP(3), AP(4), AP(5), AP(6), tokf, tokb);

    for (int l = 0; l < 3; ++l) {
        const u16* Wq_l  = AP(7)  + l * 16384;
        const u16* Wk_l  = AP(8)  + l * 16384;
        const u16* Wv1_l = AP(9)  + l * 16384;
        const u16* Wv2_l = AP(10) + l * 16384;
        const u16* Wo_l  = AP(11) + l * 16384;
        const u16* bo_l  = AP(12) + l * 128;
        const u16* g1_l  = AP(13) + l * 128;
        const u16* be1_l = AP(14) + l * 128;
        const u16* W1_l  = AP(15) + l * 65536;
        const u16* b1_l  = AP(16) + l * 512;
        const u16* W2_l  = AP(17) + l * 65536;
        const u16* b2_l  = AP(18) + l * 128;
        const u16* g2_l  = AP(19) + l * 128;
        const u16* be2_l = AP(20) + l * 128;

        for (int r = 0; r < 8 / NB; ++r) {
            size_t rowOff = (size_t)r * NB * 4096;
            gemm_qkv_kernel<<<dim3(NB * 32, 4), 512, 0, stream>>>(
                tokb + rowOff * 128, Wq_l, Wk_l, Wv1_l, Wv2_l,
                v1f, qb, kb, v2b);
            attn_s_kernel<<<NB * 256, 64, 0, stream>>>(qb, kb, sb);
            attn_o_kernel<<<dim3(NB * 4, 8, 2), 256, 0, stream>>>(sb, v1f, v2b, ob);
            gemm_ln64_kernel<<<NB * 64, 512, 0, stream>>>(
                ob, Wo_l, bo_l, tokf + rowOff * 128,
                g1_l, be1_l, tokb + rowOff * 128);
        }
        ff_kernel<<<512, 512, 0, stream>>>(tokb, W1_l, b1_l, W2_l, b2_l,
                                           g2_l, be2_l, tokf, tokb);
    }
    out_kernel<<<2, 256, 0, stream>>>(tokf, AP(21), AP(22), (float*)d_out);
}